// Round 3
// baseline (920.736 us; speedup 1.0000x reference)
//
#include <hip/hip_runtime.h>
#include <math.h>

#define HEADS 3
#define CDIM 64
#define FDIM 256
#define HC 192      // HEADS*CDIM
#define HIDDIM 128
#define NEG 0.2f

#define SCAN_BLK 256
#define SCAN_ELEMS 1024  // 4 per thread

typedef __attribute__((ext_vector_type(8))) short short8;
typedef __attribute__((ext_vector_type(4))) float f32x4;

__device__ __forceinline__ void atomicMaxF(float* addr, float val) {
    if (val >= 0.f) atomicMax((int*)addr, __float_as_int(val));
    else            atomicMin((unsigned int*)addr, __float_as_uint(val));
}

__device__ __forceinline__ unsigned short f2bf(float f) {
    unsigned int u = __float_as_uint(f);
    u = (u + 0x7FFFu + ((u >> 16) & 1u)) >> 16;   // RNE
    return (unsigned short)u;
}
__device__ __forceinline__ float bf2f(unsigned short u) {
    return __uint_as_float((unsigned int)u << 16);
}
__device__ __forceinline__ float leaky(float s) { return s >= 0.f ? s : NEG * s; }

// ---------------- f32 -> bf16 convert (n must be multiple of 4) ----------------
__global__ __launch_bounds__(256) void f32_to_bf16(const float* __restrict__ in,
                                                   unsigned short* __restrict__ out, int n4) {
    int i = blockIdx.x * blockDim.x + threadIdx.x;
    if (i >= n4) return;
    float4 v = ((const float4*)in)[i];
    ushort4 o;
    o.x = f2bf(v.x); o.y = f2bf(v.y); o.z = f2bf(v.z); o.w = f2bf(v.w);
    ((ushort4*)out)[i] = o;
}

// ---------------- bf16 MFMA GEMM: C[M,N] = A[M,K] @ B[K,N] ----------------
// 64x64 tile, 4 waves (each 16 rows x 64 cols), K step 32. K%32==0, N%64==0.
// Writes bf16 if Cbf != null else f32 to Cf.
#define ASTR 40  // shorts per LDS row (32 data + 8 pad; 80B, 16B-aligned, 2-way conflicts only)
__global__ __launch_bounds__(256) void gemm_bf16(const unsigned short* __restrict__ A,
                                                 const unsigned short* __restrict__ B,
                                                 float* __restrict__ Cf,
                                                 unsigned short* __restrict__ Cbf,
                                                 int M, int K, int N) {
    __shared__ unsigned short As[64 * ASTR];
    __shared__ unsigned short Bs[64 * ASTR];
    const int tid = threadIdx.x;
    const int wv = tid >> 6, l = tid & 63;
    const int row0 = blockIdx.x * 64, col0 = blockIdx.y * 64;
    const int arow = tid >> 2, aseg = tid & 3;   // A staging: 64 rows x 4 segs of 8
    const int bkr = tid >> 3, bcs = tid & 7;     // B staging: 32 k-rows x 8 col-segs
    const int lr = l & 15, lk = (l >> 4) * 8;
    f32x4 acc[4] = {{0.f,0.f,0.f,0.f},{0.f,0.f,0.f,0.f},{0.f,0.f,0.f,0.f},{0.f,0.f,0.f,0.f}};
    for (int k0 = 0; k0 < K; k0 += 32) {
        short8 av = {0,0,0,0,0,0,0,0};
        if (row0 + arow < M)
            av = *(const short8*)(A + (size_t)(row0 + arow) * K + k0 + aseg * 8);
        *(short8*)(As + arow * ASTR + aseg * 8) = av;
        short8 bv = *(const short8*)(B + (size_t)(k0 + bkr) * N + col0 + bcs * 8);
        #pragma unroll
        for (int j = 0; j < 8; ++j)
            Bs[(bcs * 8 + j) * ASTR + bkr] = (unsigned short)bv[j];
        __syncthreads();
        short8 af = *(const short8*)(As + (wv * 16 + lr) * ASTR + lk);
        #pragma unroll
        for (int nb = 0; nb < 4; ++nb) {
            short8 bfm = *(const short8*)(Bs + (nb * 16 + lr) * ASTR + lk);
            acc[nb] = __builtin_amdgcn_mfma_f32_16x16x32_bf16(af, bfm, acc[nb], 0, 0, 0);
        }
        __syncthreads();
    }
    const int lg = l >> 4;
    #pragma unroll
    for (int nb = 0; nb < 4; ++nb) {
        #pragma unroll
        for (int r = 0; r < 4; ++r) {
            int grow = row0 + wv * 16 + lg * 4 + r;
            int gcol = col0 + nb * 16 + lr;
            if (grow < M) {
                float x = acc[nb][r];
                if (Cbf) Cbf[(size_t)grow * N + gcol] = f2bf(x);
                else     Cf[(size_t)grow * N + gcol] = x;
            }
        }
    }
}

// ---------------- attention scores (bf16 h) + global per-head maxes ----------------
__global__ __launch_bounds__(256) void attn_scores(const unsigned short* __restrict__ Hb,
                                                   const float* __restrict__ a_src,
                                                   const float* __restrict__ a_dst,
                                                   float* __restrict__ s_src,
                                                   float* __restrict__ s_dst,
                                                   float* __restrict__ gmax, int N) {
    __shared__ float smax[24];  // [wave][6]
    int tid = threadIdx.x;
    int wave = tid >> 6, lane = tid & 63;
    int node = blockIdx.x * 4 + wave;
    if (tid < 24) smax[tid] = -1e30f;
    __syncthreads();
    if (node < N) {
        #pragma unroll
        for (int head = 0; head < HEADS; ++head) {
            float v = bf2f(Hb[(size_t)node * HC + head * CDIM + lane]);
            float ps = v * a_src[head * CDIM + lane];
            float pd = v * a_dst[head * CDIM + lane];
            #pragma unroll
            for (int off = 32; off; off >>= 1) {
                ps += __shfl_down(ps, off);
                pd += __shfl_down(pd, off);
            }
            if (lane == 0) {
                s_src[node * HEADS + head] = ps;
                s_dst[node * HEADS + head] = pd;
                smax[wave * 6 + head] = ps;
                smax[wave * 6 + 3 + head] = pd;
            }
        }
    }
    __syncthreads();
    if (tid < 6) {
        float m = fmaxf(fmaxf(smax[tid], smax[6 + tid]), fmaxf(smax[12 + tid], smax[18 + tid]));
        atomicMaxF(&gmax[tid], m);
    }
}

// ---------------- CSR build ----------------
__global__ __launch_bounds__(256) void deg_count(const int* __restrict__ ei,
                                                 int* __restrict__ deg, int E, int Etot) {
    int e = blockIdx.x * blockDim.x + threadIdx.x;
    if (e >= Etot) return;
    int dst = (e < E) ? ei[E + e] : (e - E);
    atomicAdd(&deg[dst], 1);
}

__global__ __launch_bounds__(SCAN_BLK) void scan1(const int* __restrict__ deg,
                                                  int* __restrict__ row_ptr,
                                                  int* __restrict__ bsums, int N) {
    __shared__ int sm[SCAN_BLK];
    int tid = threadIdx.x;
    int base = blockIdx.x * SCAN_ELEMS + tid * 4;
    int v[4];
    #pragma unroll
    for (int j = 0; j < 4; ++j) v[j] = (base + j < N) ? deg[base + j] : 0;
    int tsum = v[0] + v[1] + v[2] + v[3];
    sm[tid] = tsum;
    __syncthreads();
    for (int off = 1; off < SCAN_BLK; off <<= 1) {
        int y = (tid >= off) ? sm[tid - off] : 0;
        __syncthreads();
        sm[tid] += y;
        __syncthreads();
    }
    int run = sm[tid] - tsum;
    #pragma unroll
    for (int j = 0; j < 4; ++j) {
        if (base + j < N) row_ptr[base + j] = run;
        run += v[j];
    }
    if (tid == SCAN_BLK - 1) bsums[blockIdx.x] = sm[SCAN_BLK - 1];
}

__global__ __launch_bounds__(SCAN_BLK) void scan2(int* __restrict__ bsums, int nb) {
    __shared__ int sm[SCAN_BLK];
    int tid = threadIdx.x;
    int v = (tid < nb) ? bsums[tid] : 0;
    sm[tid] = v;
    __syncthreads();
    for (int off = 1; off < SCAN_BLK; off <<= 1) {
        int y = (tid >= off) ? sm[tid - off] : 0;
        __syncthreads();
        sm[tid] += y;
        __syncthreads();
    }
    if (tid < nb) bsums[tid] = sm[tid] - v;
}

__global__ __launch_bounds__(256) void scan_fixup(int* __restrict__ row_ptr,
                                                  int* __restrict__ cursor,
                                                  const int* __restrict__ bsums, int N) {
    int i = blockIdx.x * blockDim.x + threadIdx.x;
    if (i >= N) return;
    int r = row_ptr[i] + bsums[i / SCAN_ELEMS];
    row_ptr[i] = r;
    cursor[i] = r;
}

// scatter + fused numerator: p_h = exp(leaky(s_src+s_dst) - M_h), M_h = global bound
__global__ __launch_bounds__(256) void scatter_p(const int* __restrict__ ei,
                                                 const float* __restrict__ s_src,
                                                 const float* __restrict__ s_dst,
                                                 const float* __restrict__ gmax,
                                                 int* __restrict__ cursor,
                                                 float4* __restrict__ csr_data,
                                                 int E, int Etot) {
    int e = blockIdx.x * blockDim.x + threadIdx.x;
    if (e >= Etot) return;
    int src, dst;
    if (e < E) { src = ei[e]; dst = ei[E + e]; } else { src = dst = e - E; }
    float M0 = leaky(gmax[0] + gmax[3]);
    float M1 = leaky(gmax[1] + gmax[4]);
    float M2 = leaky(gmax[2] + gmax[5]);
    float p0 = __expf(leaky(s_src[src * 3 + 0] + s_dst[dst * 3 + 0]) - M0);
    float p1 = __expf(leaky(s_src[src * 3 + 1] + s_dst[dst * 3 + 1]) - M1);
    float p2 = __expf(leaky(s_src[src * 3 + 2] + s_dst[dst * 3 + 2]) - M2);
    int pos = atomicAdd(&cursor[dst], 1);
    csr_data[pos] = make_float4(__int_as_float(src), p0, p1, p2);
}

// ---------------- fused aggregation + bias + ELU (single pass, bf16 gather) ----------------
__global__ __launch_bounds__(256) void csr_agg(const int* __restrict__ row_ptr,
                                               const int* __restrict__ deg,
                                               const float4* __restrict__ csr_data,
                                               const unsigned short* __restrict__ Hb,
                                               const float* __restrict__ bias,
                                               unsigned short* __restrict__ og, int N) {
    int gid = blockIdx.x * blockDim.x + threadIdx.x;
    int node = gid >> 6, lane = gid & 63;
    if (node >= N) return;
    int start = row_ptr[node];
    int cnt = deg[node];
    float acc0 = 0.f, acc1 = 0.f, acc2 = 0.f;
    float d0 = 0.f, d1 = 0.f, d2 = 0.f;
    int i = 0;
    for (; i + 1 < cnt; i += 2) {
        float4 v0 = csr_data[start + i];
        float4 v1 = csr_data[start + i + 1];
        int s0 = __builtin_amdgcn_readfirstlane(__float_as_int(v0.x));
        int s1 = __builtin_amdgcn_readfirstlane(__float_as_int(v1.x));
        const unsigned short* r0 = Hb + (size_t)s0 * HC + lane;
        const unsigned short* r1 = Hb + (size_t)s1 * HC + lane;
        float h00 = bf2f(r0[0]), h01 = bf2f(r0[64]), h02 = bf2f(r0[128]);
        float h10 = bf2f(r1[0]), h11 = bf2f(r1[64]), h12 = bf2f(r1[128]);
        acc0 = fmaf(v0.y, h00, acc0); acc1 = fmaf(v0.z, h01, acc1); acc2 = fmaf(v0.w, h02, acc2);
        acc0 = fmaf(v1.y, h10, acc0); acc1 = fmaf(v1.z, h11, acc1); acc2 = fmaf(v1.w, h12, acc2);
        d0 += v0.y + v1.y; d1 += v0.z + v1.z; d2 += v0.w + v1.w;
    }
    if (i < cnt) {
        float4 v0 = csr_data[start + i];
        int s0 = __builtin_amdgcn_readfirstlane(__float_as_int(v0.x));
        const unsigned short* r0 = Hb + (size_t)s0 * HC + lane;
        acc0 = fmaf(v0.y, bf2f(r0[0]),   acc0);
        acc1 = fmaf(v0.z, bf2f(r0[64]),  acc1);
        acc2 = fmaf(v0.w, bf2f(r0[128]), acc2);
        d0 += v0.y; d1 += v0.z; d2 += v0.w;
    }
    float o0 = acc0 / (d0 + 1e-16f) + bias[lane];
    float o1 = acc1 / (d1 + 1e-16f) + bias[64 + lane];
    float o2 = acc2 / (d2 + 1e-16f) + bias[128 + lane];
    o0 = o0 > 0.f ? o0 : expm1f(o0);
    o1 = o1 > 0.f ? o1 : expm1f(o1);
    o2 = o2 > 0.f ? o2 : expm1f(o2);
    unsigned short* orow = og + (size_t)node * HC + lane;
    orow[0] = f2bf(o0); orow[64] = f2bf(o1); orow[128] = f2bf(o2);
}

// ---------------- MLP tail ----------------
__global__ __launch_bounds__(256) void beta_kernel(const float* __restrict__ hid,
                                                   const float* __restrict__ b1,
                                                   const float* __restrict__ w2,
                                                   const float* __restrict__ b2,
                                                   float* __restrict__ beta, int N) {
    int gid = blockIdx.x * blockDim.x + threadIdx.x;
    int row = gid >> 6, lane = gid & 63;
    if (row >= N) return;
    float acc = 0.f;
    #pragma unroll
    for (int half = 0; half < 2; ++half) {
        int j = half * 64 + lane;
        float v = hid[(size_t)row * HIDDIM + j] + b1[j];
        float g = 0.5f * v * (1.f + erff(v * 0.70710678118654752f));
        acc += g * w2[j];
    }
    #pragma unroll
    for (int off = 32; off; off >>= 1) acc += __shfl_down(acc, off);
    if (lane == 0) beta[row] = (acc + b2[0]) * 0.01f;
}

__global__ __launch_bounds__(256) void xt_beta(const float* __restrict__ X,
                                               const float* __restrict__ beta,
                                               float* __restrict__ z, int N) {
    int f = threadIdx.x;  // 256
    int nPer = (N + gridDim.x - 1) / gridDim.x;
    int n0 = blockIdx.x * nPer;
    int n1 = min(n0 + nPer, N);
    float acc = 0.f;
    for (int n = n0; n < n1; ++n)
        acc = fmaf(X[(size_t)n * FDIM + f], beta[n], acc);
    atomicAdd(&z[f], acc);
}

__global__ void final_sigmoid(const float* __restrict__ zst,
                              const float* __restrict__ zsc,
                              float* __restrict__ out) {
    int f = threadIdx.x;
    float v = zsc[f] + 0.5f * zst[f];
    out[f] = 1.f / (1.f + expf(-v));
}

extern "C" void kernel_launch(void* const* d_in, const int* in_sizes, int n_in,
                              void* d_out, int out_size, void* d_ws, size_t ws_size,
                              hipStream_t stream) {
    const float* x_st = (const float*)d_in[0];
    const int*   ei_st = (const int*)d_in[1];
    const float* x_sc = (const float*)d_in[2];
    const int*   ei_sc = (const int*)d_in[3];
    const int N = in_sizes[0] / FDIM;
    const int E = in_sizes[1] / 2;
    const int Etot = E + N;

    float* out = (float*)d_out;
    float* beta_st = out + FDIM;
    float* beta_sc = beta_st + N;

    // ---- workspace bump allocator (64B aligned) ----
    char* wp = (char*)d_ws;
    auto alloc = [&](size_t bytes) { char* r = wp; wp += (bytes + 63) & ~(size_t)63; return r; };
    float*          hid    = (float*)alloc((size_t)N * HIDDIM * 4);
    unsigned short* h_bf   = (unsigned short*)alloc((size_t)N * HC * 2);
    unsigned short* og_bf  = (unsigned short*)alloc((size_t)N * HC * 2);
    char*           xregion= alloc((size_t)N * FDIM * 2);       // x_bf, later csr_data
    unsigned short* x_bf   = (unsigned short*)xregion;
    float4*         csr_data = (float4*)xregion;                // aliases x_bf (dead after gemm1)
    unsigned short* w_bf   = (unsigned short*)alloc((size_t)FDIM * HC * 2);
    unsigned short* w1_bf  = (unsigned short*)alloc((size_t)HC * HIDDIM * 2);
    float* ssrc = (float*)alloc((size_t)N * HEADS * 4);
    float* sdst = (float*)alloc((size_t)N * HEADS * 4);
    float* gmax = (float*)alloc(8 * 4);
    float* zst  = (float*)alloc(FDIM * 4);
    float* zsc  = (float*)alloc(FDIM * 4);
    int* row_ptr = (int*)alloc((size_t)N * 4);
    int* degb    = (int*)alloc((size_t)N * 4);
    int* cursor  = (int*)alloc((size_t)N * 4);
    int* bsums   = (int*)alloc(SCAN_BLK * 4);

    const int nb_scan = (N + SCAN_ELEMS - 1) / SCAN_ELEMS;

    for (int tag = 0; tag < 2; ++tag) {
        const float* x  = tag ? x_sc : x_st;
        const int*   ei = tag ? ei_sc : ei_st;
        const float* wg   = (const float*)d_in[tag ? 12 : 4];
        const float* asrc = (const float*)d_in[tag ? 13 : 5];
        const float* adst = (const float*)d_in[tag ? 14 : 6];
        const float* bg   = (const float*)d_in[tag ? 15 : 7];
        const float* w1   = (const float*)d_in[tag ? 16 : 8];
        const float* b1   = (const float*)d_in[tag ? 17 : 9];
        const float* w2   = (const float*)d_in[tag ? 18 : 10];
        const float* b2   = (const float*)d_in[tag ? 19 : 11];
        float* beta = tag ? beta_sc : beta_st;
        float* z    = tag ? zsc : zst;

        // convert inputs/weights to bf16
        int n4x = (N * FDIM) / 4;
        f32_to_bf16<<<(n4x + 255) / 256, 256, 0, stream>>>(x, x_bf, n4x);
        f32_to_bf16<<<(FDIM * HC / 4 + 255) / 256, 256, 0, stream>>>(wg, w_bf, FDIM * HC / 4);
        f32_to_bf16<<<(HC * HIDDIM / 4 + 255) / 256, 256, 0, stream>>>(w1, w1_bf, HC * HIDDIM / 4);

        // h_bf = bf16( x_bf @ w_bf )
        dim3 g1((N + 63) / 64, HC / 64);
        gemm_bf16<<<g1, 256, 0, stream>>>(x_bf, w_bf, nullptr, h_bf, N, FDIM, HC);

        hipMemsetAsync(gmax, 0xFF, 8 * 4, stream);
        attn_scores<<<(N + 3) / 4, 256, 0, stream>>>(h_bf, asrc, adst, ssrc, sdst, gmax, N);

        // CSR build
        hipMemsetAsync(degb, 0, (size_t)N * 4, stream);
        deg_count<<<(Etot + 255) / 256, 256, 0, stream>>>(ei, degb, E, Etot);
        scan1<<<nb_scan, SCAN_BLK, 0, stream>>>(degb, row_ptr, bsums, N);
        scan2<<<1, SCAN_BLK, 0, stream>>>(bsums, nb_scan);
        scan_fixup<<<(N + 255) / 256, 256, 0, stream>>>(row_ptr, cursor, bsums, N);
        scatter_p<<<(Etot + 255) / 256, 256, 0, stream>>>(ei, ssrc, sdst, gmax, cursor,
                                                          csr_data, E, Etot);

        // fused aggregate + bias + ELU -> og_bf
        csr_agg<<<(N + 3) / 4, 256, 0, stream>>>(row_ptr, degb, csr_data, h_bf, bg, og_bf, N);

        // hid = og_bf @ w1_bf  (f32 out)
        dim3 g2((N + 63) / 64, HIDDIM / 64);
        gemm_bf16<<<g2, 256, 0, stream>>>(og_bf, w1_bf, hid, nullptr, N, HC, HIDDIM);

        beta_kernel<<<(N + 3) / 4, 256, 0, stream>>>(hid, b1, w2, b2, beta, N);

        hipMemsetAsync(z, 0, FDIM * 4, stream);
        xt_beta<<<512, 256, 0, stream>>>(x, beta, z, N);
    }
    final_sigmoid<<<1, FDIM, 0, stream>>>(zst, zsc, out);
}

// Round 4
// 611.558 us; speedup vs baseline: 1.5056x; 1.5056x over previous
//
#include <hip/hip_runtime.h>
#include <math.h>

#define HEADS 3
#define CDIM 64
#define FDIM 256
#define HC 192      // HEADS*CDIM
#define HIDDIM 128
#define NEG 0.2f

#define SCAN_BLK 256
#define SCAN_ELEMS 1024  // 4 per thread

typedef __attribute__((ext_vector_type(8))) short short8;
typedef __attribute__((ext_vector_type(4))) float f32x4;

__device__ __forceinline__ void atomicMaxF(float* addr, float val) {
    if (val >= 0.f) atomicMax((int*)addr, __float_as_int(val));
    else            atomicMin((unsigned int*)addr, __float_as_uint(val));
}

__device__ __forceinline__ unsigned short f2bf(float f) {
    unsigned int u = __float_as_uint(f);
    u = (u + 0x7FFFu + ((u >> 16) & 1u)) >> 16;   // RNE
    return (unsigned short)u;
}
__device__ __forceinline__ float bf2f(unsigned short u) {
    return __uint_as_float((unsigned int)u << 16);
}
__device__ __forceinline__ float leaky(float s) { return s >= 0.f ? s : NEG * s; }

// ---------------- f32 -> bf16 convert (n must be multiple of 4) ----------------
__global__ __launch_bounds__(256) void f32_to_bf16(const float* __restrict__ in,
                                                   unsigned short* __restrict__ out, int n4) {
    int i = blockIdx.x * blockDim.x + threadIdx.x;
    if (i >= n4) return;
    float4 v = ((const float4*)in)[i];
    ushort4 o;
    o.x = f2bf(v.x); o.y = f2bf(v.y); o.z = f2bf(v.z); o.w = f2bf(v.w);
    ((ushort4*)out)[i] = o;
}

// ---------------- bf16 MFMA GEMM: C[M,N] = A[M,K] @ B[K,N] ----------------
#define ASTR 40  // shorts per LDS row (32 data + 8 pad)
__global__ __launch_bounds__(256) void gemm_bf16(const unsigned short* __restrict__ A,
                                                 const unsigned short* __restrict__ B,
                                                 float* __restrict__ Cf,
                                                 unsigned short* __restrict__ Cbf,
                                                 int M, int K, int N) {
    __shared__ unsigned short As[64 * ASTR];
    __shared__ unsigned short Bs[64 * ASTR];
    const int tid = threadIdx.x;
    const int wv = tid >> 6, l = tid & 63;
    const int row0 = blockIdx.x * 64, col0 = blockIdx.y * 64;
    const int arow = tid >> 2, aseg = tid & 3;
    const int bkr = tid >> 3, bcs = tid & 7;
    const int lr = l & 15, lk = (l >> 4) * 8;
    f32x4 acc[4] = {{0.f,0.f,0.f,0.f},{0.f,0.f,0.f,0.f},{0.f,0.f,0.f,0.f},{0.f,0.f,0.f,0.f}};
    for (int k0 = 0; k0 < K; k0 += 32) {
        short8 av = {0,0,0,0,0,0,0,0};
        if (row0 + arow < M)
            av = *(const short8*)(A + (size_t)(row0 + arow) * K + k0 + aseg * 8);
        *(short8*)(As + arow * ASTR + aseg * 8) = av;
        short8 bv = *(const short8*)(B + (size_t)(k0 + bkr) * N + col0 + bcs * 8);
        #pragma unroll
        for (int j = 0; j < 8; ++j)
            Bs[(bcs * 8 + j) * ASTR + bkr] = (unsigned short)bv[j];
        __syncthreads();
        short8 af = *(const short8*)(As + (wv * 16 + lr) * ASTR + lk);
        #pragma unroll
        for (int nb = 0; nb < 4; ++nb) {
            short8 bfm = *(const short8*)(Bs + (nb * 16 + lr) * ASTR + lk);
            acc[nb] = __builtin_amdgcn_mfma_f32_16x16x32_bf16(af, bfm, acc[nb], 0, 0, 0);
        }
        __syncthreads();
    }
    const int lg = l >> 4;
    #pragma unroll
    for (int nb = 0; nb < 4; ++nb) {
        #pragma unroll
        for (int r = 0; r < 4; ++r) {
            int grow = row0 + wv * 16 + lg * 4 + r;
            int gcol = col0 + nb * 16 + lr;
            if (grow < M) {
                float x = acc[nb][r];
                if (Cbf) Cbf[(size_t)grow * N + gcol] = f2bf(x);
                else     Cf[(size_t)grow * N + gcol] = x;
            }
        }
    }
}

// ---------------- attention scores: grid-stride, block-level max reduction ----------------
__global__ __launch_bounds__(256) void attn_scores(const unsigned short* __restrict__ Hb,
                                                   const float* __restrict__ a_src,
                                                   const float* __restrict__ a_dst,
                                                   float* __restrict__ s_src,
                                                   float* __restrict__ s_dst,
                                                   float* __restrict__ gmax, int N) {
    __shared__ float smax[24];  // [wave][6]
    int tid = threadIdx.x;
    int wave = tid >> 6, lane = tid & 63;
    float as0 = a_src[lane], as1 = a_src[64 + lane], as2 = a_src[128 + lane];
    float ad0 = a_dst[lane], ad1 = a_dst[64 + lane], ad2 = a_dst[128 + lane];
    float m0 = -1e30f, m1 = -1e30f, m2 = -1e30f;  // src maxes (lane0 valid)
    float m3 = -1e30f, m4 = -1e30f, m5 = -1e30f;  // dst maxes
    const int stride = gridDim.x * 4;
    for (int node = blockIdx.x * 4 + wave; node < N; node += stride) {
        const unsigned short* hrow = Hb + (size_t)node * HC + lane;
        float v0 = bf2f(hrow[0]), v1 = bf2f(hrow[64]), v2 = bf2f(hrow[128]);
        float p0 = v0 * as0, p1 = v1 * as1, p2 = v2 * as2;
        float q0 = v0 * ad0, q1 = v1 * ad1, q2 = v2 * ad2;
        #pragma unroll
        for (int off = 32; off; off >>= 1) {
            p0 += __shfl_down(p0, off); p1 += __shfl_down(p1, off); p2 += __shfl_down(p2, off);
            q0 += __shfl_down(q0, off); q1 += __shfl_down(q1, off); q2 += __shfl_down(q2, off);
        }
        if (lane == 0) {
            s_src[node * 3 + 0] = p0; s_src[node * 3 + 1] = p1; s_src[node * 3 + 2] = p2;
            s_dst[node * 3 + 0] = q0; s_dst[node * 3 + 1] = q1; s_dst[node * 3 + 2] = q2;
            m0 = fmaxf(m0, p0); m1 = fmaxf(m1, p1); m2 = fmaxf(m2, p2);
            m3 = fmaxf(m3, q0); m4 = fmaxf(m4, q1); m5 = fmaxf(m5, q2);
        }
    }
    if (lane == 0) {
        smax[wave * 6 + 0] = m0; smax[wave * 6 + 1] = m1; smax[wave * 6 + 2] = m2;
        smax[wave * 6 + 3] = m3; smax[wave * 6 + 4] = m4; smax[wave * 6 + 5] = m5;
    }
    __syncthreads();
    if (tid < 6) {
        float m = fmaxf(fmaxf(smax[tid], smax[6 + tid]), fmaxf(smax[12 + tid], smax[18 + tid]));
        atomicMaxF(&gmax[tid], m);
    }
}

// ---------------- CSR build ----------------
__global__ __launch_bounds__(256) void deg_count(const int* __restrict__ ei,
                                                 int* __restrict__ deg, int E, int Etot) {
    int e = blockIdx.x * blockDim.x + threadIdx.x;
    if (e >= Etot) return;
    int dst = (e < E) ? ei[E + e] : (e - E);
    atomicAdd(&deg[dst], 1);
}

__global__ __launch_bounds__(SCAN_BLK) void scan1(const int* __restrict__ deg,
                                                  int* __restrict__ row_ptr,
                                                  int* __restrict__ bsums, int N) {
    __shared__ int sm[SCAN_BLK];
    int tid = threadIdx.x;
    int base = blockIdx.x * SCAN_ELEMS + tid * 4;
    int v[4];
    #pragma unroll
    for (int j = 0; j < 4; ++j) v[j] = (base + j < N) ? deg[base + j] : 0;
    int tsum = v[0] + v[1] + v[2] + v[3];
    sm[tid] = tsum;
    __syncthreads();
    for (int off = 1; off < SCAN_BLK; off <<= 1) {
        int y = (tid >= off) ? sm[tid - off] : 0;
        __syncthreads();
        sm[tid] += y;
        __syncthreads();
    }
    int run = sm[tid] - tsum;
    #pragma unroll
    for (int j = 0; j < 4; ++j) {
        if (base + j < N) row_ptr[base + j] = run;
        run += v[j];
    }
    if (tid == SCAN_BLK - 1) bsums[blockIdx.x] = sm[SCAN_BLK - 1];
}

__global__ __launch_bounds__(SCAN_BLK) void scan2(int* __restrict__ bsums, int nb) {
    __shared__ int sm[SCAN_BLK];
    int tid = threadIdx.x;
    int v = (tid < nb) ? bsums[tid] : 0;
    sm[tid] = v;
    __syncthreads();
    for (int off = 1; off < SCAN_BLK; off <<= 1) {
        int y = (tid >= off) ? sm[tid - off] : 0;
        __syncthreads();
        sm[tid] += y;
        __syncthreads();
    }
    if (tid < nb) bsums[tid] = sm[tid] - v;
}

__global__ __launch_bounds__(256) void scan_fixup(int* __restrict__ row_ptr,
                                                  int* __restrict__ cursor,
                                                  const int* __restrict__ bsums, int N) {
    int i = blockIdx.x * blockDim.x + threadIdx.x;
    if (i >= N) return;
    int r = row_ptr[i] + bsums[i / SCAN_ELEMS];
    row_ptr[i] = r;
    cursor[i] = r;
}

__global__ __launch_bounds__(256) void scatter_p(const int* __restrict__ ei,
                                                 const float* __restrict__ s_src,
                                                 const float* __restrict__ s_dst,
                                                 const float* __restrict__ gmax,
                                                 int* __restrict__ cursor,
                                                 float4* __restrict__ csr_data,
                                                 int E, int Etot) {
    int e = blockIdx.x * blockDim.x + threadIdx.x;
    if (e >= Etot) return;
    int src, dst;
    if (e < E) { src = ei[e]; dst = ei[E + e]; } else { src = dst = e - E; }
    float M0 = leaky(gmax[0] + gmax[3]);
    float M1 = leaky(gmax[1] + gmax[4]);
    float M2 = leaky(gmax[2] + gmax[5]);
    float p0 = __expf(leaky(s_src[src * 3 + 0] + s_dst[dst * 3 + 0]) - M0);
    float p1 = __expf(leaky(s_src[src * 3 + 1] + s_dst[dst * 3 + 1]) - M1);
    float p2 = __expf(leaky(s_src[src * 3 + 2] + s_dst[dst * 3 + 2]) - M2);
    int pos = atomicAdd(&cursor[dst], 1);
    csr_data[pos] = make_float4(__int_as_float(src), p0, p1, p2);
}

// ---------------- fused aggregation + bias + ELU (single pass, bf16 gather) ----------------
__global__ __launch_bounds__(256) void csr_agg(const int* __restrict__ row_ptr,
                                               const int* __restrict__ deg,
                                               const float4* __restrict__ csr_data,
                                               const unsigned short* __restrict__ Hb,
                                               const float* __restrict__ bias,
                                               unsigned short* __restrict__ og, int N) {
    int gid = blockIdx.x * blockDim.x + threadIdx.x;
    int node = gid >> 6, lane = gid & 63;
    if (node >= N) return;
    int start = row_ptr[node];
    int cnt = deg[node];
    float acc0 = 0.f, acc1 = 0.f, acc2 = 0.f;
    float d0 = 0.f, d1 = 0.f, d2 = 0.f;
    int i = 0;
    for (; i + 1 < cnt; i += 2) {
        float4 v0 = csr_data[start + i];
        float4 v1 = csr_data[start + i + 1];
        int s0 = __builtin_amdgcn_readfirstlane(__float_as_int(v0.x));
        int s1 = __builtin_amdgcn_readfirstlane(__float_as_int(v1.x));
        const unsigned short* r0 = Hb + (size_t)s0 * HC + lane;
        const unsigned short* r1 = Hb + (size_t)s1 * HC + lane;
        float h00 = bf2f(r0[0]), h01 = bf2f(r0[64]), h02 = bf2f(r0[128]);
        float h10 = bf2f(r1[0]), h11 = bf2f(r1[64]), h12 = bf2f(r1[128]);
        acc0 = fmaf(v0.y, h00, acc0); acc1 = fmaf(v0.z, h01, acc1); acc2 = fmaf(v0.w, h02, acc2);
        acc0 = fmaf(v1.y, h10, acc0); acc1 = fmaf(v1.z, h11, acc1); acc2 = fmaf(v1.w, h12, acc2);
        d0 += v0.y + v1.y; d1 += v0.z + v1.z; d2 += v0.w + v1.w;
    }
    if (i < cnt) {
        float4 v0 = csr_data[start + i];
        int s0 = __builtin_amdgcn_readfirstlane(__float_as_int(v0.x));
        const unsigned short* r0 = Hb + (size_t)s0 * HC + lane;
        acc0 = fmaf(v0.y, bf2f(r0[0]),   acc0);
        acc1 = fmaf(v0.z, bf2f(r0[64]),  acc1);
        acc2 = fmaf(v0.w, bf2f(r0[128]), acc2);
        d0 += v0.y; d1 += v0.z; d2 += v0.w;
    }
    float o0 = acc0 / (d0 + 1e-16f) + bias[lane];
    float o1 = acc1 / (d1 + 1e-16f) + bias[64 + lane];
    float o2 = acc2 / (d2 + 1e-16f) + bias[128 + lane];
    o0 = o0 > 0.f ? o0 : expm1f(o0);
    o1 = o1 > 0.f ? o1 : expm1f(o1);
    o2 = o2 > 0.f ? o2 : expm1f(o2);
    unsigned short* orow = og + (size_t)node * HC + lane;
    orow[0] = f2bf(o0); orow[64] = f2bf(o1); orow[128] = f2bf(o2);
}

// ---------------- MLP tail ----------------
__global__ __launch_bounds__(256) void beta_kernel(const float* __restrict__ hid,
                                                   const float* __restrict__ b1,
                                                   const float* __restrict__ w2,
                                                   const float* __restrict__ b2,
                                                   float* __restrict__ beta, int N) {
    int gid = blockIdx.x * blockDim.x + threadIdx.x;
    int row = gid >> 6, lane = gid & 63;
    if (row >= N) return;
    float acc = 0.f;
    #pragma unroll
    for (int half = 0; half < 2; ++half) {
        int j = half * 64 + lane;
        float v = hid[(size_t)row * HIDDIM + j] + b1[j];
        float g = 0.5f * v * (1.f + erff(v * 0.70710678118654752f));
        acc += g * w2[j];
    }
    #pragma unroll
    for (int off = 32; off; off >>= 1) acc += __shfl_down(acc, off);
    if (lane == 0) beta[row] = (acc + b2[0]) * 0.01f;
}

__global__ __launch_bounds__(256) void xt_beta(const float* __restrict__ X,
                                               const float* __restrict__ beta,
                                               float* __restrict__ z, int N) {
    int f = threadIdx.x;  // 256
    int nPer = (N + gridDim.x - 1) / gridDim.x;
    int n0 = blockIdx.x * nPer;
    int n1 = min(n0 + nPer, N);
    float acc = 0.f;
    for (int n = n0; n < n1; ++n)
        acc = fmaf(X[(size_t)n * FDIM + f], beta[n], acc);
    atomicAdd(&z[f], acc);
}

__global__ void final_sigmoid(const float* __restrict__ zst,
                              const float* __restrict__ zsc,
                              float* __restrict__ out) {
    int f = threadIdx.x;
    float v = zsc[f] + 0.5f * zst[f];
    out[f] = 1.f / (1.f + expf(-v));
}

extern "C" void kernel_launch(void* const* d_in, const int* in_sizes, int n_in,
                              void* d_out, int out_size, void* d_ws, size_t ws_size,
                              hipStream_t stream) {
    const float* x_st = (const float*)d_in[0];
    const int*   ei_st = (const int*)d_in[1];
    const float* x_sc = (const float*)d_in[2];
    const int*   ei_sc = (const int*)d_in[3];
    const int N = in_sizes[0] / FDIM;
    const int E = in_sizes[1] / 2;
    const int Etot = E + N;

    float* out = (float*)d_out;
    float* beta_st = out + FDIM;
    float* beta_sc = beta_st + N;

    char* wp = (char*)d_ws;
    auto alloc = [&](size_t bytes) { char* r = wp; wp += (bytes + 63) & ~(size_t)63; return r; };
    float*          hid    = (float*)alloc((size_t)N * HIDDIM * 4);
    unsigned short* h_bf   = (unsigned short*)alloc((size_t)N * HC * 2);
    unsigned short* og_bf  = (unsigned short*)alloc((size_t)N * HC * 2);
    char*           xregion= alloc((size_t)N * FDIM * 2);       // x_bf, later csr_data
    unsigned short* x_bf   = (unsigned short*)xregion;
    float4*         csr_data = (float4*)xregion;
    unsigned short* w_bf   = (unsigned short*)alloc((size_t)FDIM * HC * 2);
    unsigned short* w1_bf  = (unsigned short*)alloc((size_t)HC * HIDDIM * 2);
    float* ssrc = (float*)alloc((size_t)N * HEADS * 4);
    float* sdst = (float*)alloc((size_t)N * HEADS * 4);
    float* gmax = (float*)alloc(8 * 4);
    float* zst  = (float*)alloc(FDIM * 4);
    float* zsc  = (float*)alloc(FDIM * 4);
    int* row_ptr = (int*)alloc((size_t)N * 4);
    int* degb    = (int*)alloc((size_t)N * 4);
    int* cursor  = (int*)alloc((size_t)N * 4);
    int* bsums   = (int*)alloc(SCAN_BLK * 4);

    const int nb_scan = (N + SCAN_ELEMS - 1) / SCAN_ELEMS;

    for (int tag = 0; tag < 2; ++tag) {
        const float* x  = tag ? x_sc : x_st;
        const int*   ei = tag ? ei_sc : ei_st;
        const float* wg   = (const float*)d_in[tag ? 12 : 4];
        const float* asrc = (const float*)d_in[tag ? 13 : 5];
        const float* adst = (const float*)d_in[tag ? 14 : 6];
        const float* bg   = (const float*)d_in[tag ? 15 : 7];
        const float* w1   = (const float*)d_in[tag ? 16 : 8];
        const float* b1   = (const float*)d_in[tag ? 17 : 9];
        const float* w2   = (const float*)d_in[tag ? 18 : 10];
        const float* b2   = (const float*)d_in[tag ? 19 : 11];
        float* beta = tag ? beta_sc : beta_st;
        float* z    = tag ? zsc : zst;

        int n4x = (N * FDIM) / 4;
        f32_to_bf16<<<(n4x + 255) / 256, 256, 0, stream>>>(x, x_bf, n4x);
        f32_to_bf16<<<(FDIM * HC / 4 + 255) / 256, 256, 0, stream>>>(wg, w_bf, FDIM * HC / 4);
        f32_to_bf16<<<(HC * HIDDIM / 4 + 255) / 256, 256, 0, stream>>>(w1, w1_bf, HC * HIDDIM / 4);

        dim3 g1((N + 63) / 64, HC / 64);
        gemm_bf16<<<g1, 256, 0, stream>>>(x_bf, w_bf, nullptr, h_bf, N, FDIM, HC);

        hipMemsetAsync(gmax, 0xFF, 8 * 4, stream);
        attn_scores<<<256, 256, 0, stream>>>(h_bf, asrc, adst, ssrc, sdst, gmax, N);

        hipMemsetAsync(degb, 0, (size_t)N * 4, stream);
        deg_count<<<(Etot + 255) / 256, 256, 0, stream>>>(ei, degb, E, Etot);
        scan1<<<nb_scan, SCAN_BLK, 0, stream>>>(degb, row_ptr, bsums, N);
        scan2<<<1, SCAN_BLK, 0, stream>>>(bsums, nb_scan);
        scan_fixup<<<(N + 255) / 256, 256, 0, stream>>>(row_ptr, cursor, bsums, N);
        scatter_p<<<(Etot + 255) / 256, 256, 0, stream>>>(ei, ssrc, sdst, gmax, cursor,
                                                          csr_data, E, Etot);

        csr_agg<<<(N + 3) / 4, 256, 0, stream>>>(row_ptr, degb, csr_data, h_bf, bg, og_bf, N);

        dim3 g2((N + 63) / 64, HIDDIM / 64);
        gemm_bf16<<<g2, 256, 0, stream>>>(og_bf, w1_bf, hid, nullptr, N, HC, HIDDIM);

        beta_kernel<<<(N + 3) / 4, 256, 0, stream>>>(hid, b1, w2, b2, beta, N);

        hipMemsetAsync(z, 0, FDIM * 4, stream);
        xt_beta<<<512, 256, 0, stream>>>(x, beta, z, N);
    }
    final_sigmoid<<<1, FDIM, 0, stream>>>(zst, zsc, out);
}

// Round 5
// 503.311 us; speedup vs baseline: 1.8294x; 1.2151x over previous
//
#include <hip/hip_runtime.h>
#include <math.h>

#define HEADS 3
#define CDIM 64
#define FDIM 256
#define HC 192      // HEADS*CDIM
#define HIDDIM 128
#define NEG 0.2f

#define SCAN_BLK 256
#define SCAN_ELEMS 1024  // 4 per thread

typedef __attribute__((ext_vector_type(8))) short short8;
typedef __attribute__((ext_vector_type(4))) float f32x4;

__device__ __forceinline__ void atomicMaxF(float* addr, float val) {
    if (val >= 0.f) atomicMax((int*)addr, __float_as_int(val));
    else            atomicMin((unsigned int*)addr, __float_as_uint(val));
}

__device__ __forceinline__ unsigned short f2bf(float f) {
    unsigned int u = __float_as_uint(f);
    u = (u + 0x7FFFu + ((u >> 16) & 1u)) >> 16;   // RNE
    return (unsigned short)u;
}
__device__ __forceinline__ float bf2f(unsigned short u) {
    return __uint_as_float((unsigned int)u << 16);
}
__device__ __forceinline__ float leaky(float s) { return s >= 0.f ? s : NEG * s; }

// ---------------- MFMA GEMM: C_bf16[M,N] = A[M,K] @ B_f32[K,N] ----------------
// A is bf16 if A_BF16 else f32 (converted inline during LDS staging).
#define ASTR 40  // shorts per LDS row (32 data + 8 pad)
template <bool A_BF16>
__global__ __launch_bounds__(256) void gemm_mfma(const void* __restrict__ Ap,
                                                 const float* __restrict__ B,
                                                 unsigned short* __restrict__ Cbf,
                                                 int M, int K, int N) {
    __shared__ unsigned short As[64 * ASTR];
    __shared__ unsigned short Bs[64 * ASTR];
    const int tid = threadIdx.x;
    const int wv = tid >> 6, l = tid & 63;
    const int row0 = blockIdx.x * 64, col0 = blockIdx.y * 64;
    const int arow = tid >> 2, aseg = tid & 3;   // A: 64 rows x 4 segs of 8 elems
    const int bkr = tid >> 3, bcs = tid & 7;     // B: 32 k-rows x 8 col-segs of 8
    const int lr = l & 15, lk = (l >> 4) * 8;
    f32x4 acc[4] = {{0.f,0.f,0.f,0.f},{0.f,0.f,0.f,0.f},{0.f,0.f,0.f,0.f},{0.f,0.f,0.f,0.f}};
    for (int k0 = 0; k0 < K; k0 += 32) {
        // stage A
        short8 av = {0,0,0,0,0,0,0,0};
        if (row0 + arow < M) {
            if constexpr (A_BF16) {
                const unsigned short* A = (const unsigned short*)Ap;
                av = *(const short8*)(A + (size_t)(row0 + arow) * K + k0 + aseg * 8);
            } else {
                const float* A = (const float*)Ap;
                const float* p = A + (size_t)(row0 + arow) * K + k0 + aseg * 8;
                float4 x0 = *(const float4*)p;
                float4 x1 = *(const float4*)(p + 4);
                av[0] = (short)f2bf(x0.x); av[1] = (short)f2bf(x0.y);
                av[2] = (short)f2bf(x0.z); av[3] = (short)f2bf(x0.w);
                av[4] = (short)f2bf(x1.x); av[5] = (short)f2bf(x1.y);
                av[6] = (short)f2bf(x1.z); av[7] = (short)f2bf(x1.w);
            }
        }
        *(short8*)(As + arow * ASTR + aseg * 8) = av;
        // stage B (transpose to [col][k])
        {
            const float* p = B + (size_t)(k0 + bkr) * N + col0 + bcs * 8;
            float4 b0 = *(const float4*)p;
            float4 b1 = *(const float4*)(p + 4);
            unsigned short bw[8] = {f2bf(b0.x), f2bf(b0.y), f2bf(b0.z), f2bf(b0.w),
                                    f2bf(b1.x), f2bf(b1.y), f2bf(b1.z), f2bf(b1.w)};
            #pragma unroll
            for (int j = 0; j < 8; ++j)
                Bs[(bcs * 8 + j) * ASTR + bkr] = bw[j];
        }
        __syncthreads();
        short8 af = *(const short8*)(As + (wv * 16 + lr) * ASTR + lk);
        #pragma unroll
        for (int nb = 0; nb < 4; ++nb) {
            short8 bfm = *(const short8*)(Bs + (nb * 16 + lr) * ASTR + lk);
            acc[nb] = __builtin_amdgcn_mfma_f32_16x16x32_bf16(af, bfm, acc[nb], 0, 0, 0);
        }
        __syncthreads();
    }
    const int lg = l >> 4;
    #pragma unroll
    for (int nb = 0; nb < 4; ++nb) {
        #pragma unroll
        for (int r = 0; r < 4; ++r) {
            int grow = row0 + wv * 16 + lg * 4 + r;
            int gcol = col0 + nb * 16 + lr;
            if (grow < M) Cbf[(size_t)grow * N + gcol] = f2bf(acc[nb][r]);
        }
    }
}

// ---------------- attention scores: both tags (grid.y), grid-stride ----------------
__global__ __launch_bounds__(256) void attn_scores2(const unsigned short* __restrict__ Hall,
                                                    const float* __restrict__ as_st,
                                                    const float* __restrict__ ad_st,
                                                    const float* __restrict__ as_sc,
                                                    const float* __restrict__ ad_sc,
                                                    float* __restrict__ s_src_all,
                                                    float* __restrict__ s_dst_all,
                                                    float* __restrict__ gmax, int N) {
    __shared__ float smax[24];
    const int tag = blockIdx.y;
    const unsigned short* Hb = Hall + (size_t)tag * N * HC;
    const float* a_src = tag ? as_sc : as_st;
    const float* a_dst = tag ? ad_sc : ad_st;
    float* s_src = s_src_all + (size_t)tag * N * 3;
    float* s_dst = s_dst_all + (size_t)tag * N * 3;
    int tid = threadIdx.x;
    int wave = tid >> 6, lane = tid & 63;
    float as0 = a_src[lane], as1 = a_src[64 + lane], as2 = a_src[128 + lane];
    float ad0 = a_dst[lane], ad1 = a_dst[64 + lane], ad2 = a_dst[128 + lane];
    float m0 = -1e30f, m1 = -1e30f, m2 = -1e30f;
    float m3 = -1e30f, m4 = -1e30f, m5 = -1e30f;
    const int stride = gridDim.x * 4;
    for (int node = blockIdx.x * 4 + wave; node < N; node += stride) {
        const unsigned short* hrow = Hb + (size_t)node * HC + lane;
        float v0 = bf2f(hrow[0]), v1 = bf2f(hrow[64]), v2 = bf2f(hrow[128]);
        float p0 = v0 * as0, p1 = v1 * as1, p2 = v2 * as2;
        float q0 = v0 * ad0, q1 = v1 * ad1, q2 = v2 * ad2;
        #pragma unroll
        for (int off = 32; off; off >>= 1) {
            p0 += __shfl_down(p0, off); p1 += __shfl_down(p1, off); p2 += __shfl_down(p2, off);
            q0 += __shfl_down(q0, off); q1 += __shfl_down(q1, off); q2 += __shfl_down(q2, off);
        }
        if (lane == 0) {
            s_src[node * 3 + 0] = p0; s_src[node * 3 + 1] = p1; s_src[node * 3 + 2] = p2;
            s_dst[node * 3 + 0] = q0; s_dst[node * 3 + 1] = q1; s_dst[node * 3 + 2] = q2;
            m0 = fmaxf(m0, p0); m1 = fmaxf(m1, p1); m2 = fmaxf(m2, p2);
            m3 = fmaxf(m3, q0); m4 = fmaxf(m4, q1); m5 = fmaxf(m5, q2);
        }
    }
    if (lane == 0) {
        smax[wave * 6 + 0] = m0; smax[wave * 6 + 1] = m1; smax[wave * 6 + 2] = m2;
        smax[wave * 6 + 3] = m3; smax[wave * 6 + 4] = m4; smax[wave * 6 + 5] = m5;
    }
    __syncthreads();
    if (tid < 6) {
        float m = fmaxf(fmaxf(smax[tid], smax[6 + tid]), fmaxf(smax[12 + tid], smax[18 + tid]));
        atomicMaxF(&gmax[tag * 6 + tid], m);
    }
}

// ---------------- CSR build (both tags) ----------------
__global__ __launch_bounds__(256) void deg_count2(const int* __restrict__ ei_st,
                                                  const int* __restrict__ ei_sc,
                                                  int* __restrict__ deg, int N, int E, int Etot) {
    int e = blockIdx.x * blockDim.x + threadIdx.x;
    if (e >= Etot) return;
    const int* ei = blockIdx.y ? ei_sc : ei_st;
    int dst = (e < E) ? ei[E + e] : (e - E);
    atomicAdd(&deg[blockIdx.y * N + dst], 1);
}

__global__ __launch_bounds__(SCAN_BLK) void scan1(const int* __restrict__ deg,
                                                  int* __restrict__ row_ptr,
                                                  int* __restrict__ bsums, int N2) {
    __shared__ int sm[SCAN_BLK];
    int tid = threadIdx.x;
    int base = blockIdx.x * SCAN_ELEMS + tid * 4;
    int v[4];
    #pragma unroll
    for (int j = 0; j < 4; ++j) v[j] = (base + j < N2) ? deg[base + j] : 0;
    int tsum = v[0] + v[1] + v[2] + v[3];
    sm[tid] = tsum;
    __syncthreads();
    for (int off = 1; off < SCAN_BLK; off <<= 1) {
        int y = (tid >= off) ? sm[tid - off] : 0;
        __syncthreads();
        sm[tid] += y;
        __syncthreads();
    }
    int run = sm[tid] - tsum;
    #pragma unroll
    for (int j = 0; j < 4; ++j) {
        if (base + j < N2) row_ptr[base + j] = run;
        run += v[j];
    }
    if (tid == SCAN_BLK - 1) bsums[blockIdx.x] = sm[SCAN_BLK - 1];
}

__global__ __launch_bounds__(SCAN_BLK) void scan2(int* __restrict__ bsums, int nb) {
    __shared__ int sm[SCAN_BLK];
    int tid = threadIdx.x;
    int v = (tid < nb) ? bsums[tid] : 0;
    sm[tid] = v;
    __syncthreads();
    for (int off = 1; off < SCAN_BLK; off <<= 1) {
        int y = (tid >= off) ? sm[tid - off] : 0;
        __syncthreads();
        sm[tid] += y;
        __syncthreads();
    }
    if (tid < nb) bsums[tid] = sm[tid] - v;
}

__global__ __launch_bounds__(256) void scan_fixup(int* __restrict__ row_ptr,
                                                  int* __restrict__ cursor,
                                                  const int* __restrict__ bsums, int N2) {
    int i = blockIdx.x * blockDim.x + threadIdx.x;
    if (i >= N2) return;
    int r = row_ptr[i] + bsums[i / SCAN_ELEMS];
    row_ptr[i] = r;
    cursor[i] = r;
}

__global__ __launch_bounds__(256) void scatter_p2(const int* __restrict__ ei_st,
                                                  const int* __restrict__ ei_sc,
                                                  const float* __restrict__ s_src_all,
                                                  const float* __restrict__ s_dst_all,
                                                  const float* __restrict__ gmax,
                                                  int* __restrict__ cursor,
                                                  float4* __restrict__ csr_data,
                                                  int N, int E, int Etot) {
    int e = blockIdx.x * blockDim.x + threadIdx.x;
    if (e >= Etot) return;
    const int tag = blockIdx.y;
    const int* ei = tag ? ei_sc : ei_st;
    const float* s_src = s_src_all + (size_t)tag * N * 3;
    const float* s_dst = s_dst_all + (size_t)tag * N * 3;
    const float* gm = gmax + tag * 6;
    int src, dst;
    if (e < E) { src = ei[e]; dst = ei[E + e]; } else { src = dst = e - E; }
    float M0 = leaky(gm[0] + gm[3]);
    float M1 = leaky(gm[1] + gm[4]);
    float M2 = leaky(gm[2] + gm[5]);
    float p0 = __expf(leaky(s_src[src * 3 + 0] + s_dst[dst * 3 + 0]) - M0);
    float p1 = __expf(leaky(s_src[src * 3 + 1] + s_dst[dst * 3 + 1]) - M1);
    float p2 = __expf(leaky(s_src[src * 3 + 2] + s_dst[dst * 3 + 2]) - M2);
    int pos = atomicAdd(&cursor[tag * N + dst], 1);
    csr_data[pos] = make_float4(__int_as_float(tag * N + src), p0, p1, p2);
}

// ---------------- fused aggregation + bias + ELU (both tags, unroll-4) ----------------
__global__ __launch_bounds__(256) void csr_agg2(const int* __restrict__ row_ptr,
                                                const int* __restrict__ deg,
                                                const float4* __restrict__ csr_data,
                                                const unsigned short* __restrict__ Hall,
                                                const float* __restrict__ bias_st,
                                                const float* __restrict__ bias_sc,
                                                unsigned short* __restrict__ og, int N) {
    int gid = blockIdx.x * blockDim.x + threadIdx.x;
    int node = gid >> 6, lane = gid & 63;
    if (node >= 2 * N) return;
    const float* bias = (node >= N) ? bias_sc : bias_st;
    int start = row_ptr[node];
    int cnt = deg[node];
    float acc0 = 0.f, acc1 = 0.f, acc2 = 0.f;
    float d0 = 0.f, d1 = 0.f, d2 = 0.f;
    int i = 0;
    for (; i + 3 < cnt; i += 4) {
        float4 v0 = csr_data[start + i];
        float4 v1 = csr_data[start + i + 1];
        float4 v2 = csr_data[start + i + 2];
        float4 v3 = csr_data[start + i + 3];
        const unsigned short* r0 = Hall + (size_t)__builtin_amdgcn_readfirstlane(__float_as_int(v0.x)) * HC + lane;
        const unsigned short* r1 = Hall + (size_t)__builtin_amdgcn_readfirstlane(__float_as_int(v1.x)) * HC + lane;
        const unsigned short* r2 = Hall + (size_t)__builtin_amdgcn_readfirstlane(__float_as_int(v2.x)) * HC + lane;
        const unsigned short* r3 = Hall + (size_t)__builtin_amdgcn_readfirstlane(__float_as_int(v3.x)) * HC + lane;
        float h00 = bf2f(r0[0]), h01 = bf2f(r0[64]), h02 = bf2f(r0[128]);
        float h10 = bf2f(r1[0]), h11 = bf2f(r1[64]), h12 = bf2f(r1[128]);
        float h20 = bf2f(r2[0]), h21 = bf2f(r2[64]), h22 = bf2f(r2[128]);
        float h30 = bf2f(r3[0]), h31 = bf2f(r3[64]), h32 = bf2f(r3[128]);
        acc0 = fmaf(v0.y, h00, acc0); acc1 = fmaf(v0.z, h01, acc1); acc2 = fmaf(v0.w, h02, acc2);
        acc0 = fmaf(v1.y, h10, acc0); acc1 = fmaf(v1.z, h11, acc1); acc2 = fmaf(v1.w, h12, acc2);
        acc0 = fmaf(v2.y, h20, acc0); acc1 = fmaf(v2.z, h21, acc1); acc2 = fmaf(v2.w, h22, acc2);
        acc0 = fmaf(v3.y, h30, acc0); acc1 = fmaf(v3.z, h31, acc1); acc2 = fmaf(v3.w, h32, acc2);
        d0 += (v0.y + v1.y) + (v2.y + v3.y);
        d1 += (v0.z + v1.z) + (v2.z + v3.z);
        d2 += (v0.w + v1.w) + (v2.w + v3.w);
    }
    for (; i < cnt; ++i) {
        float4 v0 = csr_data[start + i];
        const unsigned short* r0 = Hall + (size_t)__builtin_amdgcn_readfirstlane(__float_as_int(v0.x)) * HC + lane;
        acc0 = fmaf(v0.y, bf2f(r0[0]),   acc0);
        acc1 = fmaf(v0.z, bf2f(r0[64]),  acc1);
        acc2 = fmaf(v0.w, bf2f(r0[128]), acc2);
        d0 += v0.y; d1 += v0.z; d2 += v0.w;
    }
    float o0 = acc0 / (d0 + 1e-16f) + bias[lane];
    float o1 = acc1 / (d1 + 1e-16f) + bias[64 + lane];
    float o2 = acc2 / (d2 + 1e-16f) + bias[128 + lane];
    o0 = o0 > 0.f ? o0 : expm1f(o0);
    o1 = o1 > 0.f ? o1 : expm1f(o1);
    o2 = o2 > 0.f ? o2 : expm1f(o2);
    unsigned short* orow = og + (size_t)node * HC + lane;
    orow[0] = f2bf(o0); orow[64] = f2bf(o1); orow[128] = f2bf(o2);
}

// ---------------- MLP tail (both tags) ----------------
__global__ __launch_bounds__(256) void beta2(const unsigned short* __restrict__ hid,
                                             const float* __restrict__ b1_st,
                                             const float* __restrict__ w2_st,
                                             const float* __restrict__ b2_st,
                                             const float* __restrict__ b1_sc,
                                             const float* __restrict__ w2_sc,
                                             const float* __restrict__ b2_sc,
                                             float* __restrict__ beta_out, int N) {
    int gid = blockIdx.x * blockDim.x + threadIdx.x;
    int row = gid >> 6, lane = gid & 63;
    if (row >= 2 * N) return;
    int tag = row >= N;
    const float* b1 = tag ? b1_sc : b1_st;
    const float* w2 = tag ? w2_sc : w2_st;
    const float* b2 = tag ? b2_sc : b2_st;
    unsigned int pair = *(const unsigned int*)(hid + (size_t)row * HIDDIM + lane * 2);
    float v0 = bf2f((unsigned short)(pair & 0xffffu)) + b1[lane * 2];
    float v1 = bf2f((unsigned short)(pair >> 16)) + b1[lane * 2 + 1];
    float g0 = 0.5f * v0 * (1.f + erff(v0 * 0.70710678118654752f));
    float g1 = 0.5f * v1 * (1.f + erff(v1 * 0.70710678118654752f));
    float acc = fmaf(g0, w2[lane * 2], g1 * w2[lane * 2 + 1]);
    #pragma unroll
    for (int off = 32; off; off >>= 1) acc += __shfl_down(acc, off);
    if (lane == 0) beta_out[row] = (acc + b2[0]) * 0.01f;
}

__global__ __launch_bounds__(256) void xt_beta2(const float* __restrict__ X_st,
                                                const float* __restrict__ X_sc,
                                                const float* __restrict__ beta_all,
                                                float* __restrict__ z_all, int N) {
    const int tag = blockIdx.y;
    const float* X = tag ? X_sc : X_st;
    const float* beta = beta_all + (size_t)tag * N;
    float* z = z_all + tag * FDIM;
    int f = threadIdx.x;  // 256
    int nPer = (N + gridDim.x - 1) / gridDim.x;
    int n0 = blockIdx.x * nPer;
    int n1 = min(n0 + nPer, N);
    float acc = 0.f;
    for (int n = n0; n < n1; ++n)
        acc = fmaf(X[(size_t)n * FDIM + f], beta[n], acc);
    atomicAdd(&z[f], acc);
}

__global__ void final_sigmoid(const float* __restrict__ z_all,
                              float* __restrict__ out) {
    int f = threadIdx.x;
    float v = z_all[FDIM + f] + 0.5f * z_all[f];
    out[f] = 1.f / (1.f + expf(-v));
}

extern "C" void kernel_launch(void* const* d_in, const int* in_sizes, int n_in,
                              void* d_out, int out_size, void* d_ws, size_t ws_size,
                              hipStream_t stream) {
    const float* x_st = (const float*)d_in[0];
    const int*   ei_st = (const int*)d_in[1];
    const float* x_sc = (const float*)d_in[2];
    const int*   ei_sc = (const int*)d_in[3];
    const int N = in_sizes[0] / FDIM;
    const int E = in_sizes[1] / 2;
    const int Etot = E + N;
    const int N2 = 2 * N;

    const float* wg_st   = (const float*)d_in[4];
    const float* asrc_st = (const float*)d_in[5];
    const float* adst_st = (const float*)d_in[6];
    const float* bg_st   = (const float*)d_in[7];
    const float* w1_st   = (const float*)d_in[8];
    const float* b1_st   = (const float*)d_in[9];
    const float* w2_st   = (const float*)d_in[10];
    const float* b2_st   = (const float*)d_in[11];
    const float* wg_sc   = (const float*)d_in[12];
    const float* asrc_sc = (const float*)d_in[13];
    const float* adst_sc = (const float*)d_in[14];
    const float* bg_sc   = (const float*)d_in[15];
    const float* w1_sc   = (const float*)d_in[16];
    const float* b1_sc   = (const float*)d_in[17];
    const float* w2_sc   = (const float*)d_in[18];
    const float* b2_sc   = (const float*)d_in[19];

    float* out = (float*)d_out;
    float* beta_out = out + FDIM;   // [2N] contiguous: beta_st then beta_sc

    // ---- workspace layout ----
    char* wp = (char*)d_ws;
    auto alloc = [&](size_t bytes) { char* r = wp; wp += (bytes + 63) & ~(size_t)63; return r; };
    // zero block: degb[2N] | gmax[16] | z[512]
    int*   degb = (int*)alloc(((size_t)N2 + 16 + 512) * 4);
    float* gmax = (float*)(degb + N2);
    float* zbuf = gmax + 16;
    size_t zero_bytes = ((size_t)N2 + 16 + 512) * 4;

    unsigned short* h_bf  = (unsigned short*)alloc((size_t)N2 * HC * 2);
    unsigned short* og_bf = (unsigned short*)alloc((size_t)N2 * HC * 2);
    // union: csr_data (2*Etot float4) while alive, then hid (2N*128 bf16)
    size_t csr_bytes = (size_t)2 * Etot * 16;
    size_t hid_bytes = (size_t)N2 * HIDDIM * 2;
    char* ublock = alloc(csr_bytes > hid_bytes ? csr_bytes : hid_bytes);
    float4*         csr_data = (float4*)ublock;
    unsigned short* hid      = (unsigned short*)ublock;
    float* ssrc = (float*)alloc((size_t)N2 * 3 * 4);
    float* sdst = (float*)alloc((size_t)N2 * 3 * 4);
    int* row_ptr = (int*)alloc((size_t)N2 * 4);
    int* cursor  = (int*)alloc((size_t)N2 * 4);
    int* bsums   = (int*)alloc(SCAN_BLK * 4);

    const int nb_scan = (N2 + SCAN_ELEMS - 1) / SCAN_ELEMS;

    // 1. zero degb/gmax/z
    hipMemsetAsync(degb, 0, zero_bytes, stream);

    // 2. h = bf16(x @ W) for both tags (inline f32->bf16)
    dim3 g1((N + 63) / 64, HC / 64);
    gemm_mfma<false><<<g1, 256, 0, stream>>>(x_st, wg_st, h_bf, N, FDIM, HC);
    gemm_mfma<false><<<g1, 256, 0, stream>>>(x_sc, wg_sc, h_bf + (size_t)N * HC, N, FDIM, HC);

    // 3. attention scores + global maxes (both tags)
    attn_scores2<<<dim3(128, 2), 256, 0, stream>>>(h_bf, asrc_st, adst_st, asrc_sc, adst_sc,
                                                   ssrc, sdst, gmax, N);

    // 4. CSR build over 2N
    deg_count2<<<dim3((Etot + 255) / 256, 2), 256, 0, stream>>>(ei_st, ei_sc, degb, N, E, Etot);
    scan1<<<nb_scan, SCAN_BLK, 0, stream>>>(degb, row_ptr, bsums, N2);
    scan2<<<1, SCAN_BLK, 0, stream>>>(bsums, nb_scan);
    scan_fixup<<<(N2 + 255) / 256, 256, 0, stream>>>(row_ptr, cursor, bsums, N2);
    scatter_p2<<<dim3((Etot + 255) / 256, 2), 256, 0, stream>>>(ei_st, ei_sc, ssrc, sdst, gmax,
                                                                cursor, csr_data, N, E, Etot);

    // 5. fused aggregate + bias + ELU (both tags)
    csr_agg2<<<(N2 + 3) / 4, 256, 0, stream>>>(row_ptr, degb, csr_data, h_bf,
                                               bg_st, bg_sc, og_bf, N);

    // 6. hid = bf16(og @ w1) per tag
    dim3 g2((N + 63) / 64, HIDDIM / 64);
    gemm_mfma<true><<<g2, 256, 0, stream>>>(og_bf, w1_st, hid, N, HC, HIDDIM);
    gemm_mfma<true><<<g2, 256, 0, stream>>>(og_bf + (size_t)N * HC, w1_sc,
                                            hid + (size_t)N * HIDDIM, N, HC, HIDDIM);

    // 7. beta (both tags) -> out[FDIM .. FDIM+2N)
    beta2<<<(N2 + 3) / 4, 256, 0, stream>>>(hid, b1_st, w2_st, b2_st, b1_sc, w2_sc, b2_sc,
                                            beta_out, N);

    // 8. z = x^T beta (both tags)
    xt_beta2<<<dim3(512, 2), 256, 0, stream>>>(x_st, x_sc, beta_out, zbuf, N);

    // 9. final
    final_sigmoid<<<1, FDIM, 0, stream>>>(zbuf, out);
}

// Round 6
// 423.969 us; speedup vs baseline: 2.1717x; 1.1871x over previous
//
#include <hip/hip_runtime.h>
#include <math.h>

#define HEADS 3
#define CDIM 64
#define FDIM 256
#define HC 192      // HEADS*CDIM
#define HIDDIM 128
#define NEG 0.2f

#define SCAN_BLK 256
#define SCAN_ELEMS 1024  // 4 per thread

#define ASTR2 40   // LDS stride for A tiles (32 data + 8 pad shorts)
#define BSTR 264   // LDS stride for B^T tiles (256 max K + 8 pad shorts)

typedef __attribute__((ext_vector_type(8))) short short8;
typedef __attribute__((ext_vector_type(4))) float f32x4;

__device__ __forceinline__ void atomicMaxF(float* addr, float val) {
    if (val >= 0.f) atomicMax((int*)addr, __float_as_int(val));
    else            atomicMin((unsigned int*)addr, __float_as_uint(val));
}

__device__ __forceinline__ unsigned short f2bf(float f) {
    unsigned int u = __float_as_uint(f);
    u = (u + 0x7FFFu + ((u >> 16) & 1u)) >> 16;   // RNE
    return (unsigned short)u;
}
__device__ __forceinline__ float bf2f(unsigned short u) {
    return __uint_as_float((unsigned int)u << 16);
}
__device__ __forceinline__ float leaky(float s) { return s >= 0.f ? s : NEG * s; }

// ---------------- weight transpose + bf16 convert (4 matrices, one launch) ----------------
// BT[n*K + k] = bf16(B[k*N + n])
__global__ __launch_bounds__(256) void btrans4(const float* __restrict__ wg_st,
                                               const float* __restrict__ wg_sc,
                                               const float* __restrict__ w1_st,
                                               const float* __restrict__ w1_sc,
                                               unsigned short* __restrict__ o0,
                                               unsigned short* __restrict__ o1,
                                               unsigned short* __restrict__ o2,
                                               unsigned short* __restrict__ o3) {
    int which = blockIdx.y;
    const float* src = which == 0 ? wg_st : which == 1 ? wg_sc : which == 2 ? w1_st : w1_sc;
    unsigned short* dst = which == 0 ? o0 : which == 1 ? o1 : which == 2 ? o2 : o3;
    int K  = which < 2 ? FDIM : HC;
    int Nn = which < 2 ? HC : HIDDIM;
    int total = K * Nn;
    for (int idx = blockIdx.x * 256 + threadIdx.x; idx < total; idx += gridDim.x * 256) {
        int n = idx / K, k = idx - n * K;
        dst[idx] = f2bf(src[(size_t)k * Nn + n]);
    }
}

// ---------------- GEMM1 + attention-score epilogue ----------------
// h_bf[tag] = bf16(x @ W); s_src/s_dst per (node,head) computed in-epilogue.
// grid: x = 128-row tiles, y = head (== 64-col tile), z = tag
__global__ __launch_bounds__(256) void gemm_attn(const float* __restrict__ x_st,
                                                 const float* __restrict__ x_sc,
                                                 const unsigned short* __restrict__ wgT_st,
                                                 const unsigned short* __restrict__ wgT_sc,
                                                 const float* __restrict__ as_st,
                                                 const float* __restrict__ ad_st,
                                                 const float* __restrict__ as_sc,
                                                 const float* __restrict__ ad_sc,
                                                 unsigned short* __restrict__ h_bf,
                                                 float* __restrict__ ssrc,
                                                 float* __restrict__ sdst,
                                                 int M) {
    __shared__ unsigned short As[128 * ASTR2];
    __shared__ unsigned short Bs[64 * BSTR];
    const int tag = blockIdx.z;
    const float* A = tag ? x_sc : x_st;
    const unsigned short* BT = tag ? wgT_sc : wgT_st;
    const float* a_src = tag ? as_sc : as_st;
    const float* a_dst = tag ? ad_sc : ad_st;
    const int head = blockIdx.y;
    const int row0 = blockIdx.x * 128, col0 = head * 64;
    const int tid = threadIdx.x;
    const int wv = tid >> 6, l = tid & 63;
    const int lr = l & 15, lg = l >> 4, lk = lg * 8;
    // stage B^T slice once: 64 cols x K
    {
        int c = tid >> 2, q = tid & 3;
        const unsigned short* bp = BT + (size_t)(col0 + c) * FDIM;
        #pragma unroll
        for (int kk = q * 8; kk < FDIM; kk += 32)
            *(short8*)(Bs + c * BSTR + kk) = *(const short8*)(bp + kk);
    }
    const int arow = tid >> 1, aseg = tid & 1;
    const int gr = row0 + arow;
    f32x4 acc[2][4] = {};
    for (int ks = 0; ks < FDIM / 32; ++ks) {
        int k0 = ks * 32;
        short8 av1 = {0,0,0,0,0,0,0,0}, av2 = {0,0,0,0,0,0,0,0};
        if (gr < M) {
            const float* p = A + (size_t)gr * FDIM + k0 + aseg * 16;
            float4 x0 = *(const float4*)p;
            float4 x1 = *(const float4*)(p + 4);
            float4 x2 = *(const float4*)(p + 8);
            float4 x3 = *(const float4*)(p + 12);
            av1[0] = (short)f2bf(x0.x); av1[1] = (short)f2bf(x0.y);
            av1[2] = (short)f2bf(x0.z); av1[3] = (short)f2bf(x0.w);
            av1[4] = (short)f2bf(x1.x); av1[5] = (short)f2bf(x1.y);
            av1[6] = (short)f2bf(x1.z); av1[7] = (short)f2bf(x1.w);
            av2[0] = (short)f2bf(x2.x); av2[1] = (short)f2bf(x2.y);
            av2[2] = (short)f2bf(x2.z); av2[3] = (short)f2bf(x2.w);
            av2[4] = (short)f2bf(x3.x); av2[5] = (short)f2bf(x3.y);
            av2[6] = (short)f2bf(x3.z); av2[7] = (short)f2bf(x3.w);
        }
        *(short8*)(As + arow * ASTR2 + aseg * 16) = av1;
        *(short8*)(As + arow * ASTR2 + aseg * 16 + 8) = av2;
        __syncthreads();
        #pragma unroll
        for (int m = 0; m < 2; ++m) {
            short8 af = *(const short8*)(As + (wv * 32 + m * 16 + lr) * ASTR2 + lk);
            #pragma unroll
            for (int nb = 0; nb < 4; ++nb) {
                short8 bfm = *(const short8*)(Bs + (nb * 16 + lr) * BSTR + k0 + lk);
                acc[m][nb] = __builtin_amdgcn_mfma_f32_16x16x32_bf16(af, bfm, acc[m][nb], 0, 0, 0);
            }
        }
        __syncthreads();
    }
    const size_t tagbase = (size_t)tag * M;
    // write h (bf16)
    #pragma unroll
    for (int m = 0; m < 2; ++m)
        #pragma unroll
        for (int nb = 0; nb < 4; ++nb)
            #pragma unroll
            for (int r = 0; r < 4; ++r) {
                int grow = row0 + wv * 32 + m * 16 + lg * 4 + r;
                if (grow < M)
                    h_bf[(tagbase + grow) * HC + col0 + nb * 16 + lr] = f2bf(acc[m][nb][r]);
            }
    // attention dots (full per-head dot lives in this block)
    float avs[4], avd[4];
    #pragma unroll
    for (int nb = 0; nb < 4; ++nb) {
        avs[nb] = a_src[col0 + nb * 16 + lr];
        avd[nb] = a_dst[col0 + nb * 16 + lr];
    }
    #pragma unroll
    for (int m = 0; m < 2; ++m)
        #pragma unroll
        for (int r = 0; r < 4; ++r) {
            float ds = acc[m][0][r] * avs[0] + acc[m][1][r] * avs[1]
                     + acc[m][2][r] * avs[2] + acc[m][3][r] * avs[3];
            float dd = acc[m][0][r] * avd[0] + acc[m][1][r] * avd[1]
                     + acc[m][2][r] * avd[2] + acc[m][3][r] * avd[3];
            #pragma unroll
            for (int off = 8; off; off >>= 1) {
                ds += __shfl_down(ds, off);
                dd += __shfl_down(dd, off);
            }
            int grow = row0 + wv * 32 + m * 16 + lg * 4 + r;
            if (lr == 0 && grow < M) {
                ssrc[(tagbase + grow) * 3 + head] = ds;
                sdst[(tagbase + grow) * 3 + head] = dd;
            }
        }
}

// ---------------- global per-head maxes from s arrays ----------------
__global__ __launch_bounds__(256) void gmax_reduce(const float* __restrict__ ssrc,
                                                   const float* __restrict__ sdst,
                                                   float* __restrict__ gmax, int N) {
    __shared__ float red[4][12];
    float v[12];
    #pragma unroll
    for (int j = 0; j < 12; ++j) v[j] = -1e30f;
    int stride = gridDim.x * 256;
    for (int n = blockIdx.x * 256 + threadIdx.x; n < 2 * N; n += stride) {
        float s0 = ssrc[n * 3], s1 = ssrc[n * 3 + 1], s2 = ssrc[n * 3 + 2];
        float d0 = sdst[n * 3], d1 = sdst[n * 3 + 1], d2 = sdst[n * 3 + 2];
        if (n < N) {
            v[0] = fmaxf(v[0], s0); v[1] = fmaxf(v[1], s1); v[2] = fmaxf(v[2], s2);
            v[3] = fmaxf(v[3], d0); v[4] = fmaxf(v[4], d1); v[5] = fmaxf(v[5], d2);
        } else {
            v[6] = fmaxf(v[6], s0); v[7] = fmaxf(v[7], s1); v[8] = fmaxf(v[8], s2);
            v[9] = fmaxf(v[9], d0); v[10] = fmaxf(v[10], d1); v[11] = fmaxf(v[11], d2);
        }
    }
    #pragma unroll
    for (int j = 0; j < 12; ++j)
        #pragma unroll
        for (int off = 32; off; off >>= 1)
            v[j] = fmaxf(v[j], __shfl_down(v[j], off));
    int wave = threadIdx.x >> 6, lane = threadIdx.x & 63;
    if (lane == 0) {
        #pragma unroll
        for (int j = 0; j < 12; ++j) red[wave][j] = v[j];
    }
    __syncthreads();
    if (threadIdx.x < 12) {
        float m = fmaxf(fmaxf(red[0][threadIdx.x], red[1][threadIdx.x]),
                        fmaxf(red[2][threadIdx.x], red[3][threadIdx.x]));
        atomicMaxF(&gmax[threadIdx.x], m);
    }
}

// ---------------- CSR build (both tags) ----------------
__global__ __launch_bounds__(256) void deg_count2(const int* __restrict__ ei_st,
                                                  const int* __restrict__ ei_sc,
                                                  int* __restrict__ deg, int N, int E, int Etot) {
    int e = blockIdx.x * blockDim.x + threadIdx.x;
    if (e >= Etot) return;
    const int* ei = blockIdx.y ? ei_sc : ei_st;
    int dst = (e < E) ? ei[E + e] : (e - E);
    atomicAdd(&deg[blockIdx.y * N + dst], 1);
}

__global__ __launch_bounds__(SCAN_BLK) void scan1(const int* __restrict__ deg,
                                                  int* __restrict__ row_ptr,
                                                  int* __restrict__ bsums, int N2) {
    __shared__ int sm[SCAN_BLK];
    int tid = threadIdx.x;
    int base = blockIdx.x * SCAN_ELEMS + tid * 4;
    int v[4];
    #pragma unroll
    for (int j = 0; j < 4; ++j) v[j] = (base + j < N2) ? deg[base + j] : 0;
    int tsum = v[0] + v[1] + v[2] + v[3];
    sm[tid] = tsum;
    __syncthreads();
    for (int off = 1; off < SCAN_BLK; off <<= 1) {
        int y = (tid >= off) ? sm[tid - off] : 0;
        __syncthreads();
        sm[tid] += y;
        __syncthreads();
    }
    int run = sm[tid] - tsum;
    #pragma unroll
    for (int j = 0; j < 4; ++j) {
        if (base + j < N2) row_ptr[base + j] = run;
        run += v[j];
    }
    if (tid == SCAN_BLK - 1) bsums[blockIdx.x] = sm[SCAN_BLK - 1];
}

__global__ __launch_bounds__(SCAN_BLK) void scan2(int* __restrict__ bsums, int nb) {
    __shared__ int sm[SCAN_BLK];
    int tid = threadIdx.x;
    int v = (tid < nb) ? bsums[tid] : 0;
    sm[tid] = v;
    __syncthreads();
    for (int off = 1; off < SCAN_BLK; off <<= 1) {
        int y = (tid >= off) ? sm[tid - off] : 0;
        __syncthreads();
        sm[tid] += y;
        __syncthreads();
    }
    if (tid < nb) bsums[tid] = sm[tid] - v;
}

__global__ __launch_bounds__(256) void scan_fixup(int* __restrict__ row_ptr,
                                                  int* __restrict__ cursor,
                                                  const int* __restrict__ bsums, int N2) {
    int i = blockIdx.x * blockDim.x + threadIdx.x;
    if (i >= N2) return;
    int r = row_ptr[i] + bsums[i / SCAN_ELEMS];
    row_ptr[i] = r;
    cursor[i] = r;
}

__global__ __launch_bounds__(256) void scatter_p2(const int* __restrict__ ei_st,
                                                  const int* __restrict__ ei_sc,
                                                  const float* __restrict__ s_src_all,
                                                  const float* __restrict__ s_dst_all,
                                                  const float* __restrict__ gmax,
                                                  int* __restrict__ cursor,
                                                  float4* __restrict__ csr_data,
                                                  int N, int E, int Etot) {
    int e = blockIdx.x * blockDim.x + threadIdx.x;
    if (e >= Etot) return;
    const int tag = blockIdx.y;
    const int* ei = tag ? ei_sc : ei_st;
    const float* s_src = s_src_all + (size_t)tag * N * 3;
    const float* s_dst = s_dst_all + (size_t)tag * N * 3;
    const float* gm = gmax + tag * 6;
    int src, dst;
    if (e < E) { src = ei[e]; dst = ei[E + e]; } else { src = dst = e - E; }
    float M0 = leaky(gm[0] + gm[3]);
    float M1 = leaky(gm[1] + gm[4]);
    float M2 = leaky(gm[2] + gm[5]);
    float p0 = __expf(leaky(s_src[src * 3 + 0] + s_dst[dst * 3 + 0]) - M0);
    float p1 = __expf(leaky(s_src[src * 3 + 1] + s_dst[dst * 3 + 1]) - M1);
    float p2 = __expf(leaky(s_src[src * 3 + 2] + s_dst[dst * 3 + 2]) - M2);
    int pos = atomicAdd(&cursor[tag * N + dst], 1);
    csr_data[pos] = make_float4(__int_as_float(tag * N + src), p0, p1, p2);
}

// ---------------- fused aggregation + bias + ELU (both tags, unroll-8) ----------------
__global__ __launch_bounds__(256) void csr_agg2(const int* __restrict__ row_ptr,
                                                const int* __restrict__ deg,
                                                const float4* __restrict__ csr_data,
                                                const unsigned short* __restrict__ Hall,
                                                const float* __restrict__ bias_st,
                                                const float* __restrict__ bias_sc,
                                                unsigned short* __restrict__ og, int N) {
    int gid = blockIdx.x * blockDim.x + threadIdx.x;
    int node = gid >> 6, lane = gid & 63;
    if (node >= 2 * N) return;
    const float* bias = (node >= N) ? bias_sc : bias_st;
    int start = row_ptr[node];
    int cnt = deg[node];
    float acc0 = 0.f, acc1 = 0.f, acc2 = 0.f;
    float d0 = 0.f, d1 = 0.f, d2 = 0.f;
    int i = 0;
    for (; i + 7 < cnt; i += 8) {
        float4 vv[8];
        #pragma unroll
        for (int j = 0; j < 8; ++j) vv[j] = csr_data[start + i + j];
        #pragma unroll
        for (int j = 0; j < 8; ++j) {
            const unsigned short* rp =
                Hall + (size_t)__builtin_amdgcn_readfirstlane(__float_as_int(vv[j].x)) * HC + lane;
            float h0 = bf2f(rp[0]), h1 = bf2f(rp[64]), h2 = bf2f(rp[128]);
            acc0 = fmaf(vv[j].y, h0, acc0);
            acc1 = fmaf(vv[j].z, h1, acc1);
            acc2 = fmaf(vv[j].w, h2, acc2);
            d0 += vv[j].y; d1 += vv[j].z; d2 += vv[j].w;
        }
    }
    for (; i < cnt; ++i) {
        float4 v0 = csr_data[start + i];
        const unsigned short* rp =
            Hall + (size_t)__builtin_amdgcn_readfirstlane(__float_as_int(v0.x)) * HC + lane;
        acc0 = fmaf(v0.y, bf2f(rp[0]),   acc0);
        acc1 = fmaf(v0.z, bf2f(rp[64]),  acc1);
        acc2 = fmaf(v0.w, bf2f(rp[128]), acc2);
        d0 += v0.y; d1 += v0.z; d2 += v0.w;
    }
    float o0 = acc0 / (d0 + 1e-16f) + bias[lane];
    float o1 = acc1 / (d1 + 1e-16f) + bias[64 + lane];
    float o2 = acc2 / (d2 + 1e-16f) + bias[128 + lane];
    o0 = o0 > 0.f ? o0 : expm1f(o0);
    o1 = o1 > 0.f ? o1 : expm1f(o1);
    o2 = o2 > 0.f ? o2 : expm1f(o2);
    unsigned short* orow = og + (size_t)node * HC + lane;
    orow[0] = f2bf(o0); orow[64] = f2bf(o1); orow[128] = f2bf(o2);
}

// ---------------- GEMM2 + fused gelu/dot epilogue -> beta ----------------
// grid: x = 128-row tiles, y = 64-col tile (2), z = tag. beta_out must be zeroed.
__global__ __launch_bounds__(256) void gemm_beta(const unsigned short* __restrict__ og_bf,
                                                 const unsigned short* __restrict__ w1T_st,
                                                 const unsigned short* __restrict__ w1T_sc,
                                                 const float* __restrict__ b1_st,
                                                 const float* __restrict__ w2_st,
                                                 const float* __restrict__ b2_st,
                                                 const float* __restrict__ b1_sc,
                                                 const float* __restrict__ w2_sc,
                                                 const float* __restrict__ b2_sc,
                                                 float* __restrict__ beta_out, int M) {
    __shared__ unsigned short As[128 * ASTR2];
    __shared__ unsigned short Bs[64 * BSTR];
    const int tag = blockIdx.z;
    const unsigned short* A = og_bf + (size_t)tag * M * HC;
    const unsigned short* BT = tag ? w1T_sc : w1T_st;
    const float* b1 = tag ? b1_sc : b1_st;
    const float* w2 = tag ? w2_sc : w2_st;
    const float b2h = (tag ? b2_sc : b2_st)[0] * 0.005f;  // half of b2*0.01 per col-tile
    const int row0 = blockIdx.x * 128, col0 = blockIdx.y * 64;
    const int tid = threadIdx.x;
    const int wv = tid >> 6, l = tid & 63;
    const int lr = l & 15, lg = l >> 4, lk = lg * 8;
    {
        int c = tid >> 2, q = tid & 3;
        const unsigned short* bp = BT + (size_t)(col0 + c) * HC;
        #pragma unroll
        for (int kk = q * 8; kk < HC; kk += 32)
            *(short8*)(Bs + c * BSTR + kk) = *(const short8*)(bp + kk);
    }
    const int arow = tid >> 1, aseg = tid & 1;
    const int gr = row0 + arow;
    f32x4 acc[2][4] = {};
    for (int ks = 0; ks < HC / 32; ++ks) {
        int k0 = ks * 32;
        short8 av1 = {0,0,0,0,0,0,0,0}, av2 = {0,0,0,0,0,0,0,0};
        if (gr < M) {
            const unsigned short* p = A + (size_t)gr * HC + k0 + aseg * 16;
            av1 = *(const short8*)p;
            av2 = *(const short8*)(p + 8);
        }
        *(short8*)(As + arow * ASTR2 + aseg * 16) = av1;
        *(short8*)(As + arow * ASTR2 + aseg * 16 + 8) = av2;
        __syncthreads();
        #pragma unroll
        for (int m = 0; m < 2; ++m) {
            short8 af = *(const short8*)(As + (wv * 32 + m * 16 + lr) * ASTR2 + lk);
            #pragma unroll
            for (int nb = 0; nb < 4; ++nb) {
                short8 bfm = *(const short8*)(Bs + (nb * 16 + lr) * BSTR + k0 + lk);
                acc[m][nb] = __builtin_amdgcn_mfma_f32_16x16x32_bf16(af, bfm, acc[m][nb], 0, 0, 0);
            }
        }
        __syncthreads();
    }
    float b1v[4], w2v[4];
    #pragma unroll
    for (int nb = 0; nb < 4; ++nb) {
        b1v[nb] = b1[col0 + nb * 16 + lr];
        w2v[nb] = w2[col0 + nb * 16 + lr];
    }
    #pragma unroll
    for (int m = 0; m < 2; ++m)
        #pragma unroll
        for (int r = 0; r < 4; ++r) {
            float p = 0.f;
            #pragma unroll
            for (int nb = 0; nb < 4; ++nb) {
                float vx = acc[m][nb][r] + b1v[nb];
                float g = 0.5f * vx * (1.f + erff(vx * 0.70710678118654752f));
                p = fmaf(g, w2v[nb], p);
            }
            #pragma unroll
            for (int off = 8; off; off >>= 1) p += __shfl_down(p, off);
            int grow = row0 + wv * 32 + m * 16 + lg * 4 + r;
            if (lr == 0 && grow < M)
                atomicAdd(&beta_out[(size_t)tag * M + grow], p * 0.01f + b2h);
        }
}

// ---------------- z = x^T beta (both tags) ----------------
__global__ __launch_bounds__(256) void xt_beta2(const float* __restrict__ X_st,
                                                const float* __restrict__ X_sc,
                                                const float* __restrict__ beta_all,
                                                float* __restrict__ z_all, int N) {
    const int tag = blockIdx.y;
    const float* X = tag ? X_sc : X_st;
    const float* beta = beta_all + (size_t)tag * N;
    float* z = z_all + tag * FDIM;
    int f = threadIdx.x;  // 256
    int nPer = (N + gridDim.x - 1) / gridDim.x;
    int n0 = blockIdx.x * nPer;
    int n1 = min(n0 + nPer, N);
    float acc = 0.f;
    for (int n = n0; n < n1; ++n)
        acc = fmaf(X[(size_t)n * FDIM + f], beta[n], acc);
    atomicAdd(&z[f], acc);
}

__global__ void final_sigmoid(const float* __restrict__ z_all,
                              float* __restrict__ out) {
    int f = threadIdx.x;
    float v = z_all[FDIM + f] + 0.5f * z_all[f];
    out[f] = 1.f / (1.f + expf(-v));
}

extern "C" void kernel_launch(void* const* d_in, const int* in_sizes, int n_in,
                              void* d_out, int out_size, void* d_ws, size_t ws_size,
                              hipStream_t stream) {
    const float* x_st = (const float*)d_in[0];
    const int*   ei_st = (const int*)d_in[1];
    const float* x_sc = (const float*)d_in[2];
    const int*   ei_sc = (const int*)d_in[3];
    const int N = in_sizes[0] / FDIM;
    const int E = in_sizes[1] / 2;
    const int Etot = E + N;
    const int N2 = 2 * N;

    const float* wg_st   = (const float*)d_in[4];
    const float* asrc_st = (const float*)d_in[5];
    const float* adst_st = (const float*)d_in[6];
    const float* bg_st   = (const float*)d_in[7];
    const float* w1_st   = (const float*)d_in[8];
    const float* b1_st   = (const float*)d_in[9];
    const float* w2_st   = (const float*)d_in[10];
    const float* b2_st   = (const float*)d_in[11];
    const float* wg_sc   = (const float*)d_in[12];
    const float* asrc_sc = (const float*)d_in[13];
    const float* adst_sc = (const float*)d_in[14];
    const float* bg_sc   = (const float*)d_in[15];
    const float* w1_sc   = (const float*)d_in[16];
    const float* b1_sc   = (const float*)d_in[17];
    const float* w2_sc   = (const float*)d_in[18];
    const float* b2_sc   = (const float*)d_in[19];

    float* out = (float*)d_out;
    float* beta_out = out + FDIM;   // [2N]

    // ---- workspace layout ----
    char* wp = (char*)d_ws;
    auto alloc = [&](size_t bytes) { char* r = wp; wp += (bytes + 63) & ~(size_t)63; return r; };
    int*   degb = (int*)alloc(((size_t)N2 + 16 + 512) * 4);   // zero block
    float* gmax = (float*)(degb + N2);
    float* zbuf = gmax + 16;
    size_t zero_bytes = ((size_t)N2 + 16 + 512) * 4;

    unsigned short* h_bf  = (unsigned short*)alloc((size_t)N2 * HC * 2);
    unsigned short* og_bf = (unsigned short*)alloc((size_t)N2 * HC * 2);
    float4*         csr_data = (float4*)alloc((size_t)2 * Etot * 16);
    float* ssrc = (float*)alloc((size_t)N2 * 3 * 4);
    float* sdst = (float*)alloc((size_t)N2 * 3 * 4);
    int* row_ptr = (int*)alloc((size_t)N2 * 4);
    int* cursor  = (int*)alloc((size_t)N2 * 4);
    int* bsums   = (int*)alloc(SCAN_BLK * 4);
    unsigned short* wgT_st = (unsigned short*)alloc((size_t)HC * FDIM * 2);
    unsigned short* wgT_sc = (unsigned short*)alloc((size_t)HC * FDIM * 2);
    unsigned short* w1T_st = (unsigned short*)alloc((size_t)HIDDIM * HC * 2);
    unsigned short* w1T_sc = (unsigned short*)alloc((size_t)HIDDIM * HC * 2);

    const int nb_scan = (N2 + SCAN_ELEMS - 1) / SCAN_ELEMS;
    const int nrow_t = (N + 127) / 128;

    // 1-2. zero scratch counters + beta region of d_out
    hipMemsetAsync(degb, 0, zero_bytes, stream);
    hipMemsetAsync(d_out, 0, (size_t)out_size * 4, stream);

    // 3. weight transposes (bf16)
    btrans4<<<dim3(96, 4), 256, 0, stream>>>(wg_st, wg_sc, w1_st, w1_sc,
                                             wgT_st, wgT_sc, w1T_st, w1T_sc);

    // 4. h = bf16(x @ W) + attention scores, both tags in one launch
    gemm_attn<<<dim3(nrow_t, HEADS, 2), 256, 0, stream>>>(
        x_st, x_sc, wgT_st, wgT_sc, asrc_st, adst_st, asrc_sc, adst_sc,
        h_bf, ssrc, sdst, N);

    // 5. global per-head score maxes
    gmax_reduce<<<32, 256, 0, stream>>>(ssrc, sdst, gmax, N);

    // 6-9. CSR build over 2N
    deg_count2<<<dim3((Etot + 255) / 256, 2), 256, 0, stream>>>(ei_st, ei_sc, degb, N, E, Etot);
    scan1<<<nb_scan, SCAN_BLK, 0, stream>>>(degb, row_ptr, bsums, N2);
    scan2<<<1, SCAN_BLK, 0, stream>>>(bsums, nb_scan);
    scan_fixup<<<(N2 + 255) / 256, 256, 0, stream>>>(row_ptr, cursor, bsums, N2);

    // 10. scatter edges with softmax numerators
    scatter_p2<<<dim3((Etot + 255) / 256, 2), 256, 0, stream>>>(ei_st, ei_sc, ssrc, sdst, gmax,
                                                                cursor, csr_data, N, E, Etot);

    // 11. fused aggregate + bias + ELU
    csr_agg2<<<(N2 + 3) / 4, 256, 0, stream>>>(row_ptr, degb, csr_data, h_bf,
                                               bg_st, bg_sc, og_bf, N);

    // 12. GEMM2 + gelu/dot epilogue -> beta_out
    gemm_beta<<<dim3(nrow_t, 2, 2), 256, 0, stream>>>(og_bf, w1T_st, w1T_sc,
                                                      b1_st, w2_st, b2_st,
                                                      b1_sc, w2_sc, b2_sc, beta_out, N);

    // 13. z = x^T beta
    xt_beta2<<<dim3(512, 2), 256, 0, stream>>>(x_st, x_sc, beta_out, zbuf, N);

    // 14. final
    final_sigmoid<<<1, FDIM, 0, stream>>>(zbuf, out);
}

// Round 7
// 423.550 us; speedup vs baseline: 2.1739x; 1.0010x over previous
//
#include <hip/hip_runtime.h>
#include <math.h>

#define HEADS 3
#define CDIM 64
#define FDIM 256
#define HC 192      // HEADS*CDIM
#define HIDDIM 128
#define NEG 0.2f

#define SCAN_BLK 256
#define SCAN_ELEMS 1024  // 4 per thread

#define ASTR2 40   // LDS stride for A tiles (32 data + 8 pad shorts)
#define BSTR 264   // LDS stride for B^T tiles (256 max K + 8 pad shorts)

typedef __attribute__((ext_vector_type(8))) short short8;
typedef __attribute__((ext_vector_type(4))) float f32x4;

__device__ __forceinline__ void atomicMaxF(float* addr, float val) {
    if (val >= 0.f) atomicMax((int*)addr, __float_as_int(val));
    else            atomicMin((unsigned int*)addr, __float_as_uint(val));
}

__device__ __forceinline__ unsigned short f2bf(float f) {
    unsigned int u = __float_as_uint(f);
    u = (u + 0x7FFFu + ((u >> 16) & 1u)) >> 16;   // RNE
    return (unsigned short)u;
}
__device__ __forceinline__ float bf2f(unsigned short u) {
    return __uint_as_float((unsigned int)u << 16);
}
__device__ __forceinline__ float bflo(unsigned int u) {
    return __uint_as_float(u << 16);
}
__device__ __forceinline__ float bfhi(unsigned int u) {
    return __uint_as_float(u & 0xffff0000u);
}
__device__ __forceinline__ float leaky(float s) { return s >= 0.f ? s : NEG * s; }

// ---------------- weight transpose + bf16 convert (4 matrices, one launch) ----------------
__global__ __launch_bounds__(256) void btrans4(const float* __restrict__ wg_st,
                                               const float* __restrict__ wg_sc,
                                               const float* __restrict__ w1_st,
                                               const float* __restrict__ w1_sc,
                                               unsigned short* __restrict__ o0,
                                               unsigned short* __restrict__ o1,
                                               unsigned short* __restrict__ o2,
                                               unsigned short* __restrict__ o3) {
    int which = blockIdx.y;
    const float* src = which == 0 ? wg_st : which == 1 ? wg_sc : which == 2 ? w1_st : w1_sc;
    unsigned short* dst = which == 0 ? o0 : which == 1 ? o1 : which == 2 ? o2 : o3;
    int K  = which < 2 ? FDIM : HC;
    int Nn = which < 2 ? HC : HIDDIM;
    int total = K * Nn;
    for (int idx = blockIdx.x * 256 + threadIdx.x; idx < total; idx += gridDim.x * 256) {
        int n = idx / K, k = idx - n * K;
        dst[idx] = f2bf(src[(size_t)k * Nn + n]);
    }
}

// ---------------- GEMM1 + attention-score epilogue ----------------
__global__ __launch_bounds__(256) void gemm_attn(const float* __restrict__ x_st,
                                                 const float* __restrict__ x_sc,
                                                 const unsigned short* __restrict__ wgT_st,
                                                 const unsigned short* __restrict__ wgT_sc,
                                                 const float* __restrict__ as_st,
                                                 const float* __restrict__ ad_st,
                                                 const float* __restrict__ as_sc,
                                                 const float* __restrict__ ad_sc,
                                                 unsigned short* __restrict__ h_bf,
                                                 float* __restrict__ ssrc,
                                                 float* __restrict__ sdst,
                                                 int M) {
    __shared__ unsigned short As[128 * ASTR2];
    __shared__ unsigned short Bs[64 * BSTR];
    const int tag = blockIdx.z;
    const float* A = tag ? x_sc : x_st;
    const unsigned short* BT = tag ? wgT_sc : wgT_st;
    const float* a_src = tag ? as_sc : as_st;
    const float* a_dst = tag ? ad_sc : ad_st;
    const int head = blockIdx.y;
    const int row0 = blockIdx.x * 128, col0 = head * 64;
    const int tid = threadIdx.x;
    const int wv = tid >> 6, l = tid & 63;
    const int lr = l & 15, lg = l >> 4, lk = lg * 8;
    {
        int c = tid >> 2, q = tid & 3;
        const unsigned short* bp = BT + (size_t)(col0 + c) * FDIM;
        #pragma unroll
        for (int kk = q * 8; kk < FDIM; kk += 32)
            *(short8*)(Bs + c * BSTR + kk) = *(const short8*)(bp + kk);
    }
    const int arow = tid >> 1, aseg = tid & 1;
    const int gr = row0 + arow;
    f32x4 acc[2][4] = {};
    for (int ks = 0; ks < FDIM / 32; ++ks) {
        int k0 = ks * 32;
        short8 av1 = {0,0,0,0,0,0,0,0}, av2 = {0,0,0,0,0,0,0,0};
        if (gr < M) {
            const float* p = A + (size_t)gr * FDIM + k0 + aseg * 16;
            float4 x0 = *(const float4*)p;
            float4 x1 = *(const float4*)(p + 4);
            float4 x2 = *(const float4*)(p + 8);
            float4 x3 = *(const float4*)(p + 12);
            av1[0] = (short)f2bf(x0.x); av1[1] = (short)f2bf(x0.y);
            av1[2] = (short)f2bf(x0.z); av1[3] = (short)f2bf(x0.w);
            av1[4] = (short)f2bf(x1.x); av1[5] = (short)f2bf(x1.y);
            av1[6] = (short)f2bf(x1.z); av1[7] = (short)f2bf(x1.w);
            av2[0] = (short)f2bf(x2.x); av2[1] = (short)f2bf(x2.y);
            av2[2] = (short)f2bf(x2.z); av2[3] = (short)f2bf(x2.w);
            av2[4] = (short)f2bf(x3.x); av2[5] = (short)f2bf(x3.y);
            av2[6] = (short)f2bf(x3.z); av2[7] = (short)f2bf(x3.w);
        }
        *(short8*)(As + arow * ASTR2 + aseg * 16) = av1;
        *(short8*)(As + arow * ASTR2 + aseg * 16 + 8) = av2;
        __syncthreads();
        #pragma unroll
        for (int m = 0; m < 2; ++m) {
            short8 af = *(const short8*)(As + (wv * 32 + m * 16 + lr) * ASTR2 + lk);
            #pragma unroll
            for (int nb = 0; nb < 4; ++nb) {
                short8 bfm = *(const short8*)(Bs + (nb * 16 + lr) * BSTR + k0 + lk);
                acc[m][nb] = __builtin_amdgcn_mfma_f32_16x16x32_bf16(af, bfm, acc[m][nb], 0, 0, 0);
            }
        }
        __syncthreads();
    }
    const size_t tagbase = (size_t)tag * M;
    #pragma unroll
    for (int m = 0; m < 2; ++m)
        #pragma unroll
        for (int nb = 0; nb < 4; ++nb)
            #pragma unroll
            for (int r = 0; r < 4; ++r) {
                int grow = row0 + wv * 32 + m * 16 + lg * 4 + r;
                if (grow < M)
                    h_bf[(tagbase + grow) * HC + col0 + nb * 16 + lr] = f2bf(acc[m][nb][r]);
            }
    float avs[4], avd[4];
    #pragma unroll
    for (int nb = 0; nb < 4; ++nb) {
        avs[nb] = a_src[col0 + nb * 16 + lr];
        avd[nb] = a_dst[col0 + nb * 16 + lr];
    }
    #pragma unroll
    for (int m = 0; m < 2; ++m)
        #pragma unroll
        for (int r = 0; r < 4; ++r) {
            float ds = acc[m][0][r] * avs[0] + acc[m][1][r] * avs[1]
                     + acc[m][2][r] * avs[2] + acc[m][3][r] * avs[3];
            float dd = acc[m][0][r] * avd[0] + acc[m][1][r] * avd[1]
                     + acc[m][2][r] * avd[2] + acc[m][3][r] * avd[3];
            #pragma unroll
            for (int off = 8; off; off >>= 1) {
                ds += __shfl_down(ds, off);
                dd += __shfl_down(dd, off);
            }
            int grow = row0 + wv * 32 + m * 16 + lg * 4 + r;
            if (lr == 0 && grow < M) {
                ssrc[(tagbase + grow) * 3 + head] = ds;
                sdst[(tagbase + grow) * 3 + head] = dd;
            }
        }
}

// ---------------- global per-head maxes ----------------
__global__ __launch_bounds__(256) void gmax_reduce(const float* __restrict__ ssrc,
                                                   const float* __restrict__ sdst,
                                                   float* __restrict__ gmax, int N) {
    __shared__ float red[4][12];
    float v[12];
    #pragma unroll
    for (int j = 0; j < 12; ++j) v[j] = -1e30f;
    int stride = gridDim.x * 256;
    for (int n = blockIdx.x * 256 + threadIdx.x; n < 2 * N; n += stride) {
        float s0 = ssrc[n * 3], s1 = ssrc[n * 3 + 1], s2 = ssrc[n * 3 + 2];
        float d0 = sdst[n * 3], d1 = sdst[n * 3 + 1], d2 = sdst[n * 3 + 2];
        if (n < N) {
            v[0] = fmaxf(v[0], s0); v[1] = fmaxf(v[1], s1); v[2] = fmaxf(v[2], s2);
            v[3] = fmaxf(v[3], d0); v[4] = fmaxf(v[4], d1); v[5] = fmaxf(v[5], d2);
        } else {
            v[6] = fmaxf(v[6], s0); v[7] = fmaxf(v[7], s1); v[8] = fmaxf(v[8], s2);
            v[9] = fmaxf(v[9], d0); v[10] = fmaxf(v[10], d1); v[11] = fmaxf(v[11], d2);
        }
    }
    #pragma unroll
    for (int j = 0; j < 12; ++j)
        #pragma unroll
        for (int off = 32; off; off >>= 1)
            v[j] = fmaxf(v[j], __shfl_down(v[j], off));
    int wave = threadIdx.x >> 6, lane = threadIdx.x & 63;
    if (lane == 0) {
        #pragma unroll
        for (int j = 0; j < 12; ++j) red[wave][j] = v[j];
    }
    __syncthreads();
    if (threadIdx.x < 12) {
        float m = fmaxf(fmaxf(red[0][threadIdx.x], red[1][threadIdx.x]),
                        fmaxf(red[2][threadIdx.x], red[3][threadIdx.x]));
        atomicMaxF(&gmax[threadIdx.x], m);
    }
}

// ---------------- CSR build (both tags) ----------------
__global__ __launch_bounds__(256) void deg_count2(const int* __restrict__ ei_st,
                                                  const int* __restrict__ ei_sc,
                                                  int* __restrict__ deg, int N, int E, int Etot) {
    int e = blockIdx.x * blockDim.x + threadIdx.x;
    if (e >= Etot) return;
    const int* ei = blockIdx.y ? ei_sc : ei_st;
    int dst = (e < E) ? ei[E + e] : (e - E);
    atomicAdd(&deg[blockIdx.y * N + dst], 1);
}

__global__ __launch_bounds__(SCAN_BLK) void scan1(const int* __restrict__ deg,
                                                  int* __restrict__ row_ptr,
                                                  int* __restrict__ bsums, int N2) {
    __shared__ int sm[SCAN_BLK];
    int tid = threadIdx.x;
    int base = blockIdx.x * SCAN_ELEMS + tid * 4;
    int v[4];
    #pragma unroll
    for (int j = 0; j < 4; ++j) v[j] = (base + j < N2) ? deg[base + j] : 0;
    int tsum = v[0] + v[1] + v[2] + v[3];
    sm[tid] = tsum;
    __syncthreads();
    for (int off = 1; off < SCAN_BLK; off <<= 1) {
        int y = (tid >= off) ? sm[tid - off] : 0;
        __syncthreads();
        sm[tid] += y;
        __syncthreads();
    }
    int run = sm[tid] - tsum;
    #pragma unroll
    for (int j = 0; j < 4; ++j) {
        if (base + j < N2) row_ptr[base + j] = run;
        run += v[j];
    }
    if (tid == SCAN_BLK - 1) bsums[blockIdx.x] = sm[SCAN_BLK - 1];
}

__global__ __launch_bounds__(SCAN_BLK) void scan2(int* __restrict__ bsums, int nb) {
    __shared__ int sm[SCAN_BLK];
    int tid = threadIdx.x;
    int v = (tid < nb) ? bsums[tid] : 0;
    sm[tid] = v;
    __syncthreads();
    for (int off = 1; off < SCAN_BLK; off <<= 1) {
        int y = (tid >= off) ? sm[tid - off] : 0;
        __syncthreads();
        sm[tid] += y;
        __syncthreads();
    }
    if (tid < nb) bsums[tid] = sm[tid] - v;
}

__global__ __launch_bounds__(256) void scan_fixup(int* __restrict__ row_ptr,
                                                  int* __restrict__ cursor,
                                                  const int* __restrict__ bsums, int N2) {
    int i = blockIdx.x * blockDim.x + threadIdx.x;
    if (i >= N2) return;
    int r = row_ptr[i] + bsums[i / SCAN_ELEMS];
    row_ptr[i] = r;
    cursor[i] = r;
}

__global__ __launch_bounds__(256) void scatter_p2(const int* __restrict__ ei_st,
                                                  const int* __restrict__ ei_sc,
                                                  const float* __restrict__ s_src_all,
                                                  const float* __restrict__ s_dst_all,
                                                  const float* __restrict__ gmax,
                                                  int* __restrict__ cursor,
                                                  float4* __restrict__ csr_data,
                                                  int N, int E, int Etot) {
    int e = blockIdx.x * blockDim.x + threadIdx.x;
    if (e >= Etot) return;
    const int tag = blockIdx.y;
    const int* ei = tag ? ei_sc : ei_st;
    const float* s_src = s_src_all + (size_t)tag * N * 3;
    const float* s_dst = s_dst_all + (size_t)tag * N * 3;
    const float* gm = gmax + tag * 6;
    int src, dst;
    if (e < E) { src = ei[e]; dst = ei[E + e]; } else { src = dst = e - E; }
    float M0 = leaky(gm[0] + gm[3]);
    float M1 = leaky(gm[1] + gm[4]);
    float M2 = leaky(gm[2] + gm[5]);
    float p0 = __expf(leaky(s_src[src * 3 + 0] + s_dst[dst * 3 + 0]) - M0);
    float p1 = __expf(leaky(s_src[src * 3 + 1] + s_dst[dst * 3 + 1]) - M1);
    float p2 = __expf(leaky(s_src[src * 3 + 2] + s_dst[dst * 3 + 2]) - M2);
    int pos = atomicAdd(&cursor[tag * N + dst], 1);
    csr_data[pos] = make_float4(__int_as_float(tag * N + src), p0, p1, p2);
}

// ---------------- fused aggregation + bias + ELU ----------------
// lane l<48 owns channels 4l..4l+3; whole 384B h-row fetched in ONE dwordx2 per edge.
__global__ __launch_bounds__(256) void csr_agg2(const int* __restrict__ row_ptr,
                                                const int* __restrict__ deg,
                                                const float4* __restrict__ csr_data,
                                                const unsigned short* __restrict__ Hall,
                                                const float* __restrict__ bias_st,
                                                const float* __restrict__ bias_sc,
                                                unsigned short* __restrict__ og, int N) {
    int gid = blockIdx.x * blockDim.x + threadIdx.x;
    int node = gid >> 6, lane = gid & 63;
    if (node >= 2 * N) return;
    const bool active = lane < 48;
    const int head = lane >> 4;              // 0..2 for active lanes
    int start = row_ptr[node];
    int cnt = deg[node];
    float a0 = 0.f, a1 = 0.f, a2 = 0.f, a3 = 0.f, den = 0.f;
    int i = 0;
    for (; i + 3 < cnt; i += 4) {
        float4 v0 = csr_data[start + i];
        float4 v1 = csr_data[start + i + 1];
        float4 v2 = csr_data[start + i + 2];
        float4 v3 = csr_data[start + i + 3];
        uint2 g0 = {0, 0}, g1 = {0, 0}, g2 = {0, 0}, g3 = {0, 0};
        if (active) {
            g0 = ((const uint2*)(Hall + (size_t)__builtin_amdgcn_readfirstlane(__float_as_int(v0.x)) * HC))[lane];
            g1 = ((const uint2*)(Hall + (size_t)__builtin_amdgcn_readfirstlane(__float_as_int(v1.x)) * HC))[lane];
            g2 = ((const uint2*)(Hall + (size_t)__builtin_amdgcn_readfirstlane(__float_as_int(v2.x)) * HC))[lane];
            g3 = ((const uint2*)(Hall + (size_t)__builtin_amdgcn_readfirstlane(__float_as_int(v3.x)) * HC))[lane];
        }
        float p0 = head == 0 ? v0.y : head == 1 ? v0.z : v0.w;
        float p1 = head == 0 ? v1.y : head == 1 ? v1.z : v1.w;
        float p2 = head == 0 ? v2.y : head == 1 ? v2.z : v2.w;
        float p3 = head == 0 ? v3.y : head == 1 ? v3.z : v3.w;
        den += (p0 + p1) + (p2 + p3);
        a0 = fmaf(p0, bflo(g0.x), a0); a1 = fmaf(p0, bfhi(g0.x), a1);
        a2 = fmaf(p0, bflo(g0.y), a2); a3 = fmaf(p0, bfhi(g0.y), a3);
        a0 = fmaf(p1, bflo(g1.x), a0); a1 = fmaf(p1, bfhi(g1.x), a1);
        a2 = fmaf(p1, bflo(g1.y), a2); a3 = fmaf(p1, bfhi(g1.y), a3);
        a0 = fmaf(p2, bflo(g2.x), a0); a1 = fmaf(p2, bfhi(g2.x), a1);
        a2 = fmaf(p2, bflo(g2.y), a2); a3 = fmaf(p2, bfhi(g2.y), a3);
        a0 = fmaf(p3, bflo(g3.x), a0); a1 = fmaf(p3, bfhi(g3.x), a1);
        a2 = fmaf(p3, bflo(g3.y), a2); a3 = fmaf(p3, bfhi(g3.y), a3);
    }
    for (; i < cnt; ++i) {
        float4 v0 = csr_data[start + i];
        uint2 g0 = {0, 0};
        if (active)
            g0 = ((const uint2*)(Hall + (size_t)__builtin_amdgcn_readfirstlane(__float_as_int(v0.x)) * HC))[lane];
        float p0 = head == 0 ? v0.y : head == 1 ? v0.z : v0.w;
        den += p0;
        a0 = fmaf(p0, bflo(g0.x), a0); a1 = fmaf(p0, bfhi(g0.x), a1);
        a2 = fmaf(p0, bflo(g0.y), a2); a3 = fmaf(p0, bfhi(g0.y), a3);
    }
    if (active) {
        const float* bias = (node >= N) ? bias_sc : bias_st;
        float4 bv = *(const float4*)(bias + lane * 4);
        float inv = 1.f / (den + 1e-16f);
        float o0 = fmaf(a0, inv, bv.x);
        float o1 = fmaf(a1, inv, bv.y);
        float o2 = fmaf(a2, inv, bv.z);
        float o3 = fmaf(a3, inv, bv.w);
        o0 = o0 > 0.f ? o0 : expm1f(o0);
        o1 = o1 > 0.f ? o1 : expm1f(o1);
        o2 = o2 > 0.f ? o2 : expm1f(o2);
        o3 = o3 > 0.f ? o3 : expm1f(o3);
        uint2 w;
        w.x = (unsigned int)f2bf(o0) | ((unsigned int)f2bf(o1) << 16);
        w.y = (unsigned int)f2bf(o2) | ((unsigned int)f2bf(o3) << 16);
        ((uint2*)(og + (size_t)node * HC))[lane] = w;
    }
}

// ---------------- GEMM2 + fused gelu/dot epilogue -> beta ----------------
__global__ __launch_bounds__(256) void gemm_beta(const unsigned short* __restrict__ og_bf,
                                                 const unsigned short* __restrict__ w1T_st,
                                                 const unsigned short* __restrict__ w1T_sc,
                                                 const float* __restrict__ b1_st,
                                                 const float* __restrict__ w2_st,
                                                 const float* __restrict__ b2_st,
                                                 const float* __restrict__ b1_sc,
                                                 const float* __restrict__ w2_sc,
                                                 const float* __restrict__ b2_sc,
                                                 float* __restrict__ beta_out, int M) {
    __shared__ unsigned short As[128 * ASTR2];
    __shared__ unsigned short Bs[64 * BSTR];
    const int tag = blockIdx.z;
    const unsigned short* A = og_bf + (size_t)tag * M * HC;
    const unsigned short* BT = tag ? w1T_sc : w1T_st;
    const float* b1 = tag ? b1_sc : b1_st;
    const float* w2 = tag ? w2_sc : w2_st;
    const float b2h = (tag ? b2_sc : b2_st)[0] * 0.005f;
    const int row0 = blockIdx.x * 128, col0 = blockIdx.y * 64;
    const int tid = threadIdx.x;
    const int wv = tid >> 6, l = tid & 63;
    const int lr = l & 15, lg = l >> 4, lk = lg * 8;
    {
        int c = tid >> 2, q = tid & 3;
        const unsigned short* bp = BT + (size_t)(col0 + c) * HC;
        #pragma unroll
        for (int kk = q * 8; kk < HC; kk += 32)
            *(short8*)(Bs + c * BSTR + kk) = *(const short8*)(bp + kk);
    }
    const int arow = tid >> 1, aseg = tid & 1;
    const int gr = row0 + arow;
    f32x4 acc[2][4] = {};
    for (int ks = 0; ks < HC / 32; ++ks) {
        int k0 = ks * 32;
        short8 av1 = {0,0,0,0,0,0,0,0}, av2 = {0,0,0,0,0,0,0,0};
        if (gr < M) {
            const unsigned short* p = A + (size_t)gr * HC + k0 + aseg * 16;
            av1 = *(const short8*)p;
            av2 = *(const short8*)(p + 8);
        }
        *(short8*)(As + arow * ASTR2 + aseg * 16) = av1;
        *(short8*)(As + arow * ASTR2 + aseg * 16 + 8) = av2;
        __syncthreads();
        #pragma unroll
        for (int m = 0; m < 2; ++m) {
            short8 af = *(const short8*)(As + (wv * 32 + m * 16 + lr) * ASTR2 + lk);
            #pragma unroll
            for (int nb = 0; nb < 4; ++nb) {
                short8 bfm = *(const short8*)(Bs + (nb * 16 + lr) * BSTR + k0 + lk);
                acc[m][nb] = __builtin_amdgcn_mfma_f32_16x16x32_bf16(af, bfm, acc[m][nb], 0, 0, 0);
            }
        }
        __syncthreads();
    }
    float b1v[4], w2v[4];
    #pragma unroll
    for (int nb = 0; nb < 4; ++nb) {
        b1v[nb] = b1[col0 + nb * 16 + lr];
        w2v[nb] = w2[col0 + nb * 16 + lr];
    }
    #pragma unroll
    for (int m = 0; m < 2; ++m)
        #pragma unroll
        for (int r = 0; r < 4; ++r) {
            float p = 0.f;
            #pragma unroll
            for (int nb = 0; nb < 4; ++nb) {
                float vx = acc[m][nb][r] + b1v[nb];
                float g = 0.5f * vx * (1.f + erff(vx * 0.70710678118654752f));
                p = fmaf(g, w2v[nb], p);
            }
            #pragma unroll
            for (int off = 8; off; off >>= 1) p += __shfl_down(p, off);
            int grow = row0 + wv * 32 + m * 16 + lg * 4 + r;
            if (lr == 0 && grow < M)
                atomicAdd(&beta_out[(size_t)tag * M + grow], p * 0.01f + b2h);
        }
}

// ---------------- z = x^T beta (both tags) ----------------
__global__ __launch_bounds__(256) void xt_beta2(const float* __restrict__ X_st,
                                                const float* __restrict__ X_sc,
                                                const float* __restrict__ beta_all,
                                                float* __restrict__ z_all, int N) {
    const int tag = blockIdx.y;
    const float* X = tag ? X_sc : X_st;
    const float* beta = beta_all + (size_t)tag * N;
    float* z = z_all + tag * FDIM;
    int f = threadIdx.x;  // 256
    int nPer = (N + gridDim.x - 1) / gridDim.x;
    int n0 = blockIdx.x * nPer;
    int n1 = min(n0 + nPer, N);
    float acc = 0.f;
    for (int n = n0; n < n1; ++n)
        acc = fmaf(X[(size_t)n * FDIM + f], beta[n], acc);
    atomicAdd(&z[f], acc);
}

__global__ void final_sigmoid(const float* __restrict__ z_all,
                              float* __restrict__ out) {
    int f = threadIdx.x;
    float v = z_all[FDIM + f] + 0.5f * z_all[f];
    out[f] = 1.f / (1.f + expf(-v));
}

extern "C" void kernel_launch(void* const* d_in, const int* in_sizes, int n_in,
                              void* d_out, int out_size, void* d_ws, size_t ws_size,
                              hipStream_t stream) {
    const float* x_st = (const float*)d_in[0];
    const int*   ei_st = (const int*)d_in[1];
    const float* x_sc = (const float*)d_in[2];
    const int*   ei_sc = (const int*)d_in[3];
    const int N = in_sizes[0] / FDIM;
    const int E = in_sizes[1] / 2;
    const int Etot = E + N;
    const int N2 = 2 * N;

    const float* wg_st   = (const float*)d_in[4];
    const float* asrc_st = (const float*)d_in[5];
    const float* adst_st = (const float*)d_in[6];
    const float* bg_st   = (const float*)d_in[7];
    const float* w1_st   = (const float*)d_in[8];
    const float* b1_st   = (const float*)d_in[9];
    const float* w2_st   = (const float*)d_in[10];
    const float* b2_st   = (const float*)d_in[11];
    const float* wg_sc   = (const float*)d_in[12];
    const float* asrc_sc = (const float*)d_in[13];
    const float* adst_sc = (const float*)d_in[14];
    const float* bg_sc   = (const float*)d_in[15];
    const float* w1_sc   = (const float*)d_in[16];
    const float* b1_sc   = (const float*)d_in[17];
    const float* w2_sc   = (const float*)d_in[18];
    const float* b2_sc   = (const float*)d_in[19];

    float* out = (float*)d_out;
    float* beta_out = out + FDIM;   // [2N]

    char* wp = (char*)d_ws;
    auto alloc = [&](size_t bytes) { char* r = wp; wp += (bytes + 63) & ~(size_t)63; return r; };
    int*   degb = (int*)alloc(((size_t)N2 + 16 + 512) * 4);
    float* gmax = (float*)(degb + N2);
    float* zbuf = gmax + 16;
    size_t zero_bytes = ((size_t)N2 + 16 + 512) * 4;

    unsigned short* h_bf  = (unsigned short*)alloc((size_t)N2 * HC * 2);
    unsigned short* og_bf = (unsigned short*)alloc((size_t)N2 * HC * 2);
    float4*         csr_data = (float4*)alloc((size_t)2 * Etot * 16);
    float* ssrc = (float*)alloc((size_t)N2 * 3 * 4);
    float* sdst = (float*)alloc((size_t)N2 * 3 * 4);
    int* row_ptr = (int*)alloc((size_t)N2 * 4);
    int* cursor  = (int*)alloc((size_t)N2 * 4);
    int* bsums   = (int*)alloc(SCAN_BLK * 4);
    unsigned short* wgT_st = (unsigned short*)alloc((size_t)HC * FDIM * 2);
    unsigned short* wgT_sc = (unsigned short*)alloc((size_t)HC * FDIM * 2);
    unsigned short* w1T_st = (unsigned short*)alloc((size_t)HIDDIM * HC * 2);
    unsigned short* w1T_sc = (unsigned short*)alloc((size_t)HIDDIM * HC * 2);

    const int nb_scan = (N2 + SCAN_ELEMS - 1) / SCAN_ELEMS;
    const int nrow_t = (N + 127) / 128;

    hipMemsetAsync(degb, 0, zero_bytes, stream);
    hipMemsetAsync(d_out, 0, (size_t)out_size * 4, stream);

    btrans4<<<dim3(96, 4), 256, 0, stream>>>(wg_st, wg_sc, w1_st, w1_sc,
                                             wgT_st, wgT_sc, w1T_st, w1T_sc);

    gemm_attn<<<dim3(nrow_t, HEADS, 2), 256, 0, stream>>>(
        x_st, x_sc, wgT_st, wgT_sc, asrc_st, adst_st, asrc_sc, adst_sc,
        h_bf, ssrc, sdst, N);

    gmax_reduce<<<32, 256, 0, stream>>>(ssrc, sdst, gmax, N);

    deg_count2<<<dim3((Etot + 255) / 256, 2), 256, 0, stream>>>(ei_st, ei_sc, degb, N, E, Etot);
    scan1<<<nb_scan, SCAN_BLK, 0, stream>>>(degb, row_ptr, bsums, N2);
    scan2<<<1, SCAN_BLK, 0, stream>>>(bsums, nb_scan);
    scan_fixup<<<(N2 + 255) / 256, 256, 0, stream>>>(row_ptr, cursor, bsums, N2);

    scatter_p2<<<dim3((Etot + 255) / 256, 2), 256, 0, stream>>>(ei_st, ei_sc, ssrc, sdst, gmax,
                                                                cursor, csr_data, N, E, Etot);

    csr_agg2<<<(N2 + 3) / 4, 256, 0, stream>>>(row_ptr, degb, csr_data, h_bf,
                                               bg_st, bg_sc, og_bf, N);

    gemm_beta<<<dim3(nrow_t, 2, 2), 256, 0, stream>>>(og_bf, w1T_st, w1T_sc,
                                                      b1_st, w2_st, b2_st,
                                                      b1_sc, w2_sc, b2_sc, beta_out, N);

    xt_beta2<<<dim3(512, 2), 256, 0, stream>>>(x_st, x_sc, beta_out, zbuf, N);

    final_sigmoid<<<1, FDIM, 0, stream>>>(zbuf, out);
}

// Round 8
// 390.074 us; speedup vs baseline: 2.3604x; 1.0858x over previous
//
#include <hip/hip_runtime.h>
#include <math.h>

#define HEADS 3
#define CDIM 64
#define FDIM 256
#define HC 192      // HEADS*CDIM
#define HIDDIM 128
#define NEG 0.2f

#define SCAN_BLK 256
#define SCAN_ELEMS 1024  // 4 per thread; csr_agg/scatter use >>10

#define ASTR2 40   // LDS stride for A tiles (32 data + 8 pad shorts)
#define BSTR 264   // LDS stride for B^T tiles (256 max K + 8 pad shorts)

typedef __attribute__((ext_vector_type(8))) short short8;
typedef __attribute__((ext_vector_type(4))) float f32x4;

__device__ __forceinline__ void atomicMaxF(float* addr, float val) {
    if (val >= 0.f) atomicMax((int*)addr, __float_as_int(val));
    else            atomicMin((unsigned int*)addr, __float_as_uint(val));
}

__device__ __forceinline__ unsigned short f2bf(float f) {
    unsigned int u = __float_as_uint(f);
    u = (u + 0x7FFFu + ((u >> 16) & 1u)) >> 16;   // RNE
    return (unsigned short)u;
}
__device__ __forceinline__ float bf2f(unsigned short u) {
    return __uint_as_float((unsigned int)u << 16);
}
__device__ __forceinline__ float leaky(float s) { return s >= 0.f ? s : NEG * s; }

// bijective chunked XCD swizzle (m204): consecutive wgid chunks per XCD
__device__ __forceinline__ int xcd_swizzle(int orig, int nwg) {
    int q = nwg >> 3, r = nwg & 7;
    int xcd = orig & 7, idx = orig >> 3;
    return (xcd < r ? xcd * (q + 1) : r * (q + 1) + (xcd - r) * q) + idx;
}

// ---------------- weight transpose + bf16 convert ----------------
__global__ __launch_bounds__(256) void btrans4(const float* __restrict__ wg_st,
                                               const float* __restrict__ wg_sc,
                                               const float* __restrict__ w1_st,
                                               const float* __restrict__ w1_sc,
                                               unsigned short* __restrict__ o0,
                                               unsigned short* __restrict__ o1,
                                               unsigned short* __restrict__ o2,
                                               unsigned short* __restrict__ o3) {
    int which = blockIdx.y;
    const float* src = which == 0 ? wg_st : which == 1 ? wg_sc : which == 2 ? w1_st : w1_sc;
    unsigned short* dst = which == 0 ? o0 : which == 1 ? o1 : which == 2 ? o2 : o3;
    int K  = which < 2 ? FDIM : HC;
    int Nn = which < 2 ? HC : HIDDIM;
    int total = K * Nn;
    for (int idx = blockIdx.x * 256 + threadIdx.x; idx < total; idx += gridDim.x * 256) {
        int n = idx / K, k = idx - n * K;
        dst[idx] = f2bf(src[(size_t)k * Nn + n]);
    }
}

// ---------------- GEMM1 + attention-score epilogue (flattened, XCD-swizzled) ----------------
__global__ __launch_bounds__(256) void gemm_attn(const float* __restrict__ x_st,
                                                 const float* __restrict__ x_sc,
                                                 const unsigned short* __restrict__ wgT_st,
                                                 const unsigned short* __restrict__ wgT_sc,
                                                 const float* __restrict__ as_st,
                                                 const float* __restrict__ ad_st,
                                                 const float* __restrict__ as_sc,
                                                 const float* __restrict__ ad_sc,
                                                 unsigned short* __restrict__ h_bf,
                                                 float* __restrict__ ssrc,
                                                 float* __restrict__ sdst,
                                                 int M, int nrow) {
    __shared__ unsigned short As[128 * ASTR2];
    __shared__ unsigned short Bs[64 * BSTR];
    const int nwg = nrow * HEADS * 2;
    const int wgid = xcd_swizzle(blockIdx.x, nwg);
    const int tag = wgid / (nrow * HEADS);
    const int rem = wgid - tag * (nrow * HEADS);
    const int rt = rem / HEADS;
    const int head = rem - rt * HEADS;
    const float* A = tag ? x_sc : x_st;
    const unsigned short* BT = tag ? wgT_sc : wgT_st;
    const float* a_src = tag ? as_sc : as_st;
    const float* a_dst = tag ? ad_sc : ad_st;
    const int row0 = rt * 128, col0 = head * 64;
    const int tid = threadIdx.x;
    const int wv = tid >> 6, l = tid & 63;
    const int lr = l & 15, lg = l >> 4, lk = lg * 8;
    {
        int c = tid >> 2, q = tid & 3;
        const unsigned short* bp = BT + (size_t)(col0 + c) * FDIM;
        #pragma unroll
        for (int kk = q * 8; kk < FDIM; kk += 32)
            *(short8*)(Bs + c * BSTR + kk) = *(const short8*)(bp + kk);
    }
    const int arow = tid >> 1, aseg = tid & 1;
    const int gr = row0 + arow;
    f32x4 acc[2][4] = {};
    for (int ks = 0; ks < FDIM / 32; ++ks) {
        int k0 = ks * 32;
        short8 av1 = {0,0,0,0,0,0,0,0}, av2 = {0,0,0,0,0,0,0,0};
        if (gr < M) {
            const float* p = A + (size_t)gr * FDIM + k0 + aseg * 16;
            float4 x0 = *(const float4*)p;
            float4 x1 = *(const float4*)(p + 4);
            float4 x2 = *(const float4*)(p + 8);
            float4 x3 = *(const float4*)(p + 12);
            av1[0] = (short)f2bf(x0.x); av1[1] = (short)f2bf(x0.y);
            av1[2] = (short)f2bf(x0.z); av1[3] = (short)f2bf(x0.w);
            av1[4] = (short)f2bf(x1.x); av1[5] = (short)f2bf(x1.y);
            av1[6] = (short)f2bf(x1.z); av1[7] = (short)f2bf(x1.w);
            av2[0] = (short)f2bf(x2.x); av2[1] = (short)f2bf(x2.y);
            av2[2] = (short)f2bf(x2.z); av2[3] = (short)f2bf(x2.w);
            av2[4] = (short)f2bf(x3.x); av2[5] = (short)f2bf(x3.y);
            av2[6] = (short)f2bf(x3.z); av2[7] = (short)f2bf(x3.w);
        }
        *(short8*)(As + arow * ASTR2 + aseg * 16) = av1;
        *(short8*)(As + arow * ASTR2 + aseg * 16 + 8) = av2;
        __syncthreads();
        #pragma unroll
        for (int m = 0; m < 2; ++m) {
            short8 af = *(const short8*)(As + (wv * 32 + m * 16 + lr) * ASTR2 + lk);
            #pragma unroll
            for (int nb = 0; nb < 4; ++nb) {
                short8 bfm = *(const short8*)(Bs + (nb * 16 + lr) * BSTR + k0 + lk);
                acc[m][nb] = __builtin_amdgcn_mfma_f32_16x16x32_bf16(af, bfm, acc[m][nb], 0, 0, 0);
            }
        }
        __syncthreads();
    }
    const size_t tagbase = (size_t)tag * M;
    #pragma unroll
    for (int m = 0; m < 2; ++m)
        #pragma unroll
        for (int nb = 0; nb < 4; ++nb)
            #pragma unroll
            for (int r = 0; r < 4; ++r) {
                int grow = row0 + wv * 32 + m * 16 + lg * 4 + r;
                if (grow < M)
                    h_bf[(tagbase + grow) * HC + col0 + nb * 16 + lr] = f2bf(acc[m][nb][r]);
            }
    float avs[4], avd[4];
    #pragma unroll
    for (int nb = 0; nb < 4; ++nb) {
        avs[nb] = a_src[col0 + nb * 16 + lr];
        avd[nb] = a_dst[col0 + nb * 16 + lr];
    }
    #pragma unroll
    for (int m = 0; m < 2; ++m)
        #pragma unroll
        for (int r = 0; r < 4; ++r) {
            float ds = acc[m][0][r] * avs[0] + acc[m][1][r] * avs[1]
                     + acc[m][2][r] * avs[2] + acc[m][3][r] * avs[3];
            float dd = acc[m][0][r] * avd[0] + acc[m][1][r] * avd[1]
                     + acc[m][2][r] * avd[2] + acc[m][3][r] * avd[3];
            #pragma unroll
            for (int off = 8; off; off >>= 1) {
                ds += __shfl_down(ds, off);
                dd += __shfl_down(dd, off);
            }
            int grow = row0 + wv * 32 + m * 16 + lg * 4 + r;
            if (lr == 0 && grow < M) {
                ssrc[(tagbase + grow) * 3 + head] = ds;
                sdst[(tagbase + grow) * 3 + head] = dd;
            }
        }
}

// ---------------- prep: degree counts (y=0,1) + global score maxes (y=2) ----------------
__global__ __launch_bounds__(256) void prep(const int* __restrict__ ei_st,
                                            const int* __restrict__ ei_sc,
                                            int* __restrict__ deg,
                                            const float* __restrict__ ssrc,
                                            const float* __restrict__ sdst,
                                            float* __restrict__ gmax,
                                            int N, int E, int Etot) {
    if (blockIdx.y < 2) {
        int e = blockIdx.x * 256 + threadIdx.x;
        if (e >= Etot) return;
        const int* ei = blockIdx.y ? ei_sc : ei_st;
        int dst = (e < E) ? ei[E + e] : (e - E);
        atomicAdd(&deg[blockIdx.y * N + dst], 1);
        return;
    }
    if (blockIdx.x >= 32) return;   // keep gmax atomics at 32 blocks (contention trap, R3)
    __shared__ float red[4][12];
    float v[12];
    #pragma unroll
    for (int j = 0; j < 12; ++j) v[j] = -1e30f;
    const int stride = 32 * 256;
    for (int n = blockIdx.x * 256 + threadIdx.x; n < 2 * N; n += stride) {
        float s0 = ssrc[n * 3], s1 = ssrc[n * 3 + 1], s2 = ssrc[n * 3 + 2];
        float d0 = sdst[n * 3], d1 = sdst[n * 3 + 1], d2 = sdst[n * 3 + 2];
        if (n < N) {
            v[0] = fmaxf(v[0], s0); v[1] = fmaxf(v[1], s1); v[2] = fmaxf(v[2], s2);
            v[3] = fmaxf(v[3], d0); v[4] = fmaxf(v[4], d1); v[5] = fmaxf(v[5], d2);
        } else {
            v[6] = fmaxf(v[6], s0); v[7] = fmaxf(v[7], s1); v[8] = fmaxf(v[8], s2);
            v[9] = fmaxf(v[9], d0); v[10] = fmaxf(v[10], d1); v[11] = fmaxf(v[11], d2);
        }
    }
    #pragma unroll
    for (int j = 0; j < 12; ++j)
        #pragma unroll
        for (int off = 32; off; off >>= 1)
            v[j] = fmaxf(v[j], __shfl_down(v[j], off));
    int wave = threadIdx.x >> 6, lane = threadIdx.x & 63;
    if (lane == 0) {
        #pragma unroll
        for (int j = 0; j < 12; ++j) red[wave][j] = v[j];
    }
    __syncthreads();
    if (threadIdx.x < 12) {
        float m = fmaxf(fmaxf(red[0][threadIdx.x], red[1][threadIdx.x]),
                        fmaxf(red[2][threadIdx.x], red[3][threadIdx.x]));
        atomicMaxF(&gmax[threadIdx.x], m);
    }
}

// ---------------- scan (local) + block sums ----------------
__global__ __launch_bounds__(SCAN_BLK) void scan1(const int* __restrict__ deg,
                                                  int* __restrict__ row_ptr,
                                                  int* __restrict__ bsums, int N2) {
    __shared__ int sm[SCAN_BLK];
    int tid = threadIdx.x;
    int base = blockIdx.x * SCAN_ELEMS + tid * 4;
    int v[4];
    #pragma unroll
    for (int j = 0; j < 4; ++j) v[j] = (base + j < N2) ? deg[base + j] : 0;
    int tsum = v[0] + v[1] + v[2] + v[3];
    sm[tid] = tsum;
    __syncthreads();
    for (int off = 1; off < SCAN_BLK; off <<= 1) {
        int y = (tid >= off) ? sm[tid - off] : 0;
        __syncthreads();
        sm[tid] += y;
        __syncthreads();
    }
    int run = sm[tid] - tsum;
    #pragma unroll
    for (int j = 0; j < 4; ++j) {
        if (base + j < N2) row_ptr[base + j] = run;
        run += v[j];
    }
    if (tid == SCAN_BLK - 1) bsums[blockIdx.x] = sm[SCAN_BLK - 1];
}

__global__ __launch_bounds__(SCAN_BLK) void scan2(int* __restrict__ bsums, int nb) {
    __shared__ int sm[SCAN_BLK];
    int tid = threadIdx.x;
    int v = (tid < nb) ? bsums[tid] : 0;
    sm[tid] = v;
    __syncthreads();
    for (int off = 1; off < SCAN_BLK; off <<= 1) {
        int y = (tid >= off) ? sm[tid - off] : 0;
        __syncthreads();
        sm[tid] += y;
        __syncthreads();
    }
    if (tid < nb) bsums[tid] = sm[tid] - v;
}

// ---------------- scatter with on-the-fly row_ptr fixup ----------------
__global__ __launch_bounds__(256) void scatter_p2(const int* __restrict__ ei_st,
                                                  const int* __restrict__ ei_sc,
                                                  const float* __restrict__ s_src_all,
                                                  const float* __restrict__ s_dst_all,
                                                  const float* __restrict__ gmax,
                                                  const int* __restrict__ row_ptr,
                                                  const int* __restrict__ bsums,
                                                  int* __restrict__ cursor,
                                                  float4* __restrict__ csr_data,
                                                  int N, int E, int Etot) {
    int e = blockIdx.x * blockDim.x + threadIdx.x;
    if (e >= Etot) return;
    const int tag = blockIdx.y;
    const int* ei = tag ? ei_sc : ei_st;
    const float* s_src = s_src_all + (size_t)tag * N * 3;
    const float* s_dst = s_dst_all + (size_t)tag * N * 3;
    const float* gm = gmax + tag * 6;
    int src, dst;
    if (e < E) { src = ei[e]; dst = ei[E + e]; } else { src = dst = e - E; }
    float M0 = leaky(gm[0] + gm[3]);
    float M1 = leaky(gm[1] + gm[4]);
    float M2 = leaky(gm[2] + gm[5]);
    float p0 = __expf(leaky(s_src[src * 3 + 0] + s_dst[dst * 3 + 0]) - M0);
    float p1 = __expf(leaky(s_src[src * 3 + 1] + s_dst[dst * 3 + 1]) - M1);
    float p2 = __expf(leaky(s_src[src * 3 + 2] + s_dst[dst * 3 + 2]) - M2);
    int g = tag * N + dst;
    int pos = row_ptr[g] + bsums[g >> 10] + atomicAdd(&cursor[g], 1);
    csr_data[pos] = make_float4(__int_as_float(tag * N + src), p0, p1, p2);
}

// ---------------- fused aggregation + bias + ELU (round-5 shape: 3xushort, unroll-4) ----------------
__global__ __launch_bounds__(256) void csr_agg2(const int* __restrict__ row_ptr,
                                                const int* __restrict__ bsums,
                                                const int* __restrict__ deg,
                                                const float4* __restrict__ csr_data,
                                                const unsigned short* __restrict__ Hall,
                                                const float* __restrict__ bias_st,
                                                const float* __restrict__ bias_sc,
                                                unsigned short* __restrict__ og, int N) {
    int gid = blockIdx.x * blockDim.x + threadIdx.x;
    int node = gid >> 6, lane = gid & 63;
    if (node >= 2 * N) return;
    const float* bias = (node >= N) ? bias_sc : bias_st;
    int start = row_ptr[node] + bsums[node >> 10];
    int cnt = deg[node];
    float acc0 = 0.f, acc1 = 0.f, acc2 = 0.f;
    float d0 = 0.f, d1 = 0.f, d2 = 0.f;
    int i = 0;
    for (; i + 3 < cnt; i += 4) {
        float4 v0 = csr_data[start + i];
        float4 v1 = csr_data[start + i + 1];
        float4 v2 = csr_data[start + i + 2];
        float4 v3 = csr_data[start + i + 3];
        const unsigned short* r0 =
            Hall + (size_t)__builtin_amdgcn_readfirstlane(__float_as_int(v0.x)) * HC + lane;
        const unsigned short* r1 =
            Hall + (size_t)__builtin_amdgcn_readfirstlane(__float_as_int(v1.x)) * HC + lane;
        const unsigned short* r2 =
            Hall + (size_t)__builtin_amdgcn_readfirstlane(__float_as_int(v2.x)) * HC + lane;
        const unsigned short* r3 =
            Hall + (size_t)__builtin_amdgcn_readfirstlane(__float_as_int(v3.x)) * HC + lane;
        float h00 = bf2f(r0[0]), h01 = bf2f(r0[64]), h02 = bf2f(r0[128]);
        float h10 = bf2f(r1[0]), h11 = bf2f(r1[64]), h12 = bf2f(r1[128]);
        float h20 = bf2f(r2[0]), h21 = bf2f(r2[64]), h22 = bf2f(r2[128]);
        float h30 = bf2f(r3[0]), h31 = bf2f(r3[64]), h32 = bf2f(r3[128]);
        acc0 = fmaf(v0.y, h00, acc0); acc1 = fmaf(v0.z, h01, acc1); acc2 = fmaf(v0.w, h02, acc2);
        acc0 = fmaf(v1.y, h10, acc0); acc1 = fmaf(v1.z, h11, acc1); acc2 = fmaf(v1.w, h12, acc2);
        acc0 = fmaf(v2.y, h20, acc0); acc1 = fmaf(v2.z, h21, acc1); acc2 = fmaf(v2.w, h22, acc2);
        acc0 = fmaf(v3.y, h30, acc0); acc1 = fmaf(v3.z, h31, acc1); acc2 = fmaf(v3.w, h32, acc2);
        d0 += (v0.y + v1.y) + (v2.y + v3.y);
        d1 += (v0.z + v1.z) + (v2.z + v3.z);
        d2 += (v0.w + v1.w) + (v2.w + v3.w);
    }
    for (; i < cnt; ++i) {
        float4 v0 = csr_data[start + i];
        const unsigned short* r0 =
            Hall + (size_t)__builtin_amdgcn_readfirstlane(__float_as_int(v0.x)) * HC + lane;
        acc0 = fmaf(v0.y, bf2f(r0[0]),   acc0);
        acc1 = fmaf(v0.z, bf2f(r0[64]),  acc1);
        acc2 = fmaf(v0.w, bf2f(r0[128]), acc2);
        d0 += v0.y; d1 += v0.z; d2 += v0.w;
    }
    float o0 = acc0 / (d0 + 1e-16f) + bias[lane];
    float o1 = acc1 / (d1 + 1e-16f) + bias[64 + lane];
    float o2 = acc2 / (d2 + 1e-16f) + bias[128 + lane];
    o0 = o0 > 0.f ? o0 : expm1f(o0);
    o1 = o1 > 0.f ? o1 : expm1f(o1);
    o2 = o2 > 0.f ? o2 : expm1f(o2);
    unsigned short* orow = og + (size_t)node * HC + lane;
    orow[0] = f2bf(o0); orow[64] = f2bf(o1); orow[128] = f2bf(o2);
}

// ---------------- GEMM2 + fused gelu/dot epilogue (flattened, XCD-swizzled) ----------------
__global__ __launch_bounds__(256) void gemm_beta(const unsigned short* __restrict__ og_bf,
                                                 const unsigned short* __restrict__ w1T_st,
                                                 const unsigned short* __restrict__ w1T_sc,
                                                 const float* __restrict__ b1_st,
                                                 const float* __restrict__ w2_st,
                                                 const float* __restrict__ b2_st,
                                                 const float* __restrict__ b1_sc,
                                                 const float* __restrict__ w2_sc,
                                                 const float* __restrict__ b2_sc,
                                                 float* __restrict__ beta_out,
                                                 int M, int nrow) {
    __shared__ unsigned short As[128 * ASTR2];
    __shared__ unsigned short Bs[64 * BSTR];
    const int nwg = nrow * 2 * 2;
    const int wgid = xcd_swizzle(blockIdx.x, nwg);
    const int tag = wgid / (nrow * 2);
    const int rem = wgid - tag * (nrow * 2);
    const int rt = rem >> 1;
    const int ct = rem & 1;
    const unsigned short* A = og_bf + (size_t)tag * M * HC;
    const unsigned short* BT = tag ? w1T_sc : w1T_st;
    const float* b1 = tag ? b1_sc : b1_st;
    const float* w2 = tag ? w2_sc : w2_st;
    const float b2h = (tag ? b2_sc : b2_st)[0] * 0.005f;
    const int row0 = rt * 128, col0 = ct * 64;
    const int tid = threadIdx.x;
    const int wv = tid >> 6, l = tid & 63;
    const int lr = l & 15, lg = l >> 4, lk = lg * 8;
    {
        int c = tid >> 2, q = tid & 3;
        const unsigned short* bp = BT + (size_t)(col0 + c) * HC;
        #pragma unroll
        for (int kk = q * 8; kk < HC; kk += 32)
            *(short8*)(Bs + c * BSTR + kk) = *(const short8*)(bp + kk);
    }
    const int arow = tid >> 1, aseg = tid & 1;
    const int gr = row0 + arow;
    f32x4 acc[2][4] = {};
    for (int ks = 0; ks < HC / 32; ++ks) {
        int k0 = ks * 32;
        short8 av1 = {0,0,0,0,0,0,0,0}, av2 = {0,0,0,0,0,0,0,0};
        if (gr < M) {
            const unsigned short* p = A + (size_t)gr * HC + k0 + aseg * 16;
            av1 = *(const short8*)p;
            av2 = *(const short8*)(p + 8);
        }
        *(short8*)(As + arow * ASTR2 + aseg * 16) = av1;
        *(short8*)(As + arow * ASTR2 + aseg * 16 + 8) = av2;
        __syncthreads();
        #pragma unroll
        for (int m = 0; m < 2; ++m) {
            short8 af = *(const short8*)(As + (wv * 32 + m * 16 + lr) * ASTR2 + lk);
            #pragma unroll
            for (int nb = 0; nb < 4; ++nb) {
                short8 bfm = *(const short8*)(Bs + (nb * 16 + lr) * BSTR + k0 + lk);
                acc[m][nb] = __builtin_amdgcn_mfma_f32_16x16x32_bf16(af, bfm, acc[m][nb], 0, 0, 0);
            }
        }
        __syncthreads();
    }
    float b1v[4], w2v[4];
    #pragma unroll
    for (int nb = 0; nb < 4; ++nb) {
        b1v[nb] = b1[col0 + nb * 16 + lr];
        w2v[nb] = w2[col0 + nb * 16 + lr];
    }
    #pragma unroll
    for (int m = 0; m < 2; ++m)
        #pragma unroll
        for (int r = 0; r < 4; ++r) {
            float p = 0.f;
            #pragma unroll
            for (int nb = 0; nb < 4; ++nb) {
                float vx = acc[m][nb][r] + b1v[nb];
                float g = 0.5f * vx * (1.f + erff(vx * 0.70710678118654752f));
                p = fmaf(g, w2v[nb], p);
            }
            #pragma unroll
            for (int off = 8; off; off >>= 1) p += __shfl_down(p, off);
            int grow = row0 + wv * 32 + m * 16 + lg * 4 + r;
            if (lr == 0 && grow < M)
                atomicAdd(&beta_out[(size_t)tag * M + grow], p * 0.01f + b2h);
        }
}

// ---------------- z = x^T beta ----------------
__global__ __launch_bounds__(256) void xt_beta2(const float* __restrict__ X_st,
                                                const float* __restrict__ X_sc,
                                                const float* __restrict__ beta_all,
                                                float* __restrict__ z_all, int N) {
    const int tag = blockIdx.y;
    const float* X = tag ? X_sc : X_st;
    const float* beta = beta_all + (size_t)tag * N;
    float* z = z_all + tag * FDIM;
    int f = threadIdx.x;  // 256
    int nPer = (N + gridDim.x - 1) / gridDim.x;
    int n0 = blockIdx.x * nPer;
    int n1 = min(n0 + nPer, N);
    float acc = 0.f;
    for (int n = n0; n < n1; ++n)
        acc = fmaf(X[(size_t)n * FDIM + f], beta[n], acc);
    atomicAdd(&z[f], acc);
}

__global__ void final_sigmoid(const float* __restrict__ z_all,
                              float* __restrict__ out) {
    int f = threadIdx.x;
    float v = z_all[FDIM + f] + 0.5f * z_all[f];
    out[f] = 1.f / (1.f + expf(-v));
}

extern "C" void kernel_launch(void* const* d_in, const int* in_sizes, int n_in,
                              void* d_out, int out_size, void* d_ws, size_t ws_size,
                              hipStream_t stream) {
    const float* x_st = (const float*)d_in[0];
    const int*   ei_st = (const int*)d_in[1];
    const float* x_sc = (const float*)d_in[2];
    const int*   ei_sc = (const int*)d_in[3];
    const int N = in_sizes[0] / FDIM;
    const int E = in_sizes[1] / 2;
    const int Etot = E + N;
    const int N2 = 2 * N;

    const float* wg_st   = (const float*)d_in[4];
    const float* asrc_st = (const float*)d_in[5];
    const float* adst_st = (const float*)d_in[6];
    const float* bg_st   = (const float*)d_in[7];
    const float* w1_st   = (const float*)d_in[8];
    const float* b1_st   = (const float*)d_in[9];
    const float* w2_st   = (const float*)d_in[10];
    const float* b2_st   = (const float*)d_in[11];
    const float* wg_sc   = (const float*)d_in[12];
    const float* asrc_sc = (const float*)d_in[13];
    const float* adst_sc = (const float*)d_in[14];
    const float* bg_sc   = (const float*)d_in[15];
    const float* w1_sc   = (const float*)d_in[16];
    const float* b1_sc   = (const float*)d_in[17];
    const float* w2_sc   = (const float*)d_in[18];
    const float* b2_sc   = (const float*)d_in[19];

    float* out = (float*)d_out;
    float* beta_out = out + FDIM;   // [2N]

    char* wp = (char*)d_ws;
    auto alloc = [&](size_t bytes) { char* r = wp; wp += (bytes + 63) & ~(size_t)63; return r; };
    // zero block: degb[2N] | cursor[2N] | gmax[16] | zbuf[512]
    int*   degb   = (int*)alloc(((size_t)2 * N2 + 16 + 512) * 4);
    int*   cursor = degb + N2;
    float* gmax   = (float*)(cursor + N2);
    float* zbuf   = gmax + 16;
    size_t zero_bytes = ((size_t)2 * N2 + 16 + 512) * 4;

    unsigned short* h_bf  = (unsigned short*)alloc((size_t)N2 * HC * 2);
    unsigned short* og_bf = (unsigned short*)alloc((size_t)N2 * HC * 2);
    float4*         csr_data = (float4*)alloc((size_t)2 * Etot * 16);
    float* ssrc = (float*)alloc((size_t)N2 * 3 * 4);
    float* sdst = (float*)alloc((size_t)N2 * 3 * 4);
    int* row_ptr = (int*)alloc((size_t)N2 * 4);
    int* bsums   = (int*)alloc(SCAN_BLK * 4);
    unsigned short* wgT_st = (unsigned short*)alloc((size_t)HC * FDIM * 2);
    unsigned short* wgT_sc = (unsigned short*)alloc((size_t)HC * FDIM * 2);
    unsigned short* w1T_st = (unsigned short*)alloc((size_t)HIDDIM * HC * 2);
    unsigned short* w1T_sc = (unsigned short*)alloc((size_t)HIDDIM * HC * 2);

    const int nb_scan = (N2 + SCAN_ELEMS - 1) / SCAN_ELEMS;
    const int nrow_t = (N + 127) / 128;

    hipMemsetAsync(degb, 0, zero_bytes, stream);
    hipMemsetAsync(d_out, 0, (size_t)out_size * 4, stream);

    btrans4<<<dim3(96, 4), 256, 0, stream>>>(wg_st, wg_sc, w1_st, w1_sc,
                                             wgT_st, wgT_sc, w1T_st, w1T_sc);

    gemm_attn<<<nrow_t * HEADS * 2, 256, 0, stream>>>(
        x_st, x_sc, wgT_st, wgT_sc, asrc_st, adst_st, asrc_sc, adst_sc,
        h_bf, ssrc, sdst, N, nrow_t);

    // deg counts (y=0,1) + gmax (y=2, first 32 blocks)
    prep<<<dim3((Etot + 255) / 256, 3), 256, 0, stream>>>(ei_st, ei_sc, degb,
                                                          ssrc, sdst, gmax, N, E, Etot);

    scan1<<<nb_scan, SCAN_BLK, 0, stream>>>(degb, row_ptr, bsums, N2);
    scan2<<<1, SCAN_BLK, 0, stream>>>(bsums, nb_scan);

    scatter_p2<<<dim3((Etot + 255) / 256, 2), 256, 0, stream>>>(
        ei_st, ei_sc, ssrc, sdst, gmax, row_ptr, bsums, cursor, csr_data, N, E, Etot);

    csr_agg2<<<(N2 + 3) / 4, 256, 0, stream>>>(row_ptr, bsums, degb, csr_data, h_bf,
                                               bg_st, bg_sc, og_bf, N);

    gemm_beta<<<nrow_t * 2 * 2, 256, 0, stream>>>(og_bf, w1T_st, w1T_sc,
                                                  b1_st, w2_st, b2_st,
                                                  b1_sc, w2_sc, b2_sc, beta_out, N, nrow_t);

    xt_beta2<<<dim3(512, 2), 256, 0, stream>>>(x_st, x_sc, beta_out, zbuf, N);

    final_sigmoid<<<1, FDIM, 0, stream>>>(zbuf, out);
}